// Round 2
// baseline (925.639 us; speedup 1.0000x reference)
//
#include <hip/hip_runtime.h>
#include <hip/hip_bf16.h>
#include <cstdint>
#include <cstddef>

#define DEV __device__ __forceinline__

typedef float f32x4 __attribute__((ext_vector_type(4)));
typedef short s16x8 __attribute__((ext_vector_type(8)));
typedef short s16x4 __attribute__((ext_vector_type(4)));
typedef __bf16 bf16x8 __attribute__((ext_vector_type(8)));

DEV unsigned short f2bf(float f) {
  union { float f; unsigned u; } v; v.f = f;
  return (unsigned short)((v.u + 0x7FFFu + ((v.u >> 16) & 1u)) >> 16);
}
DEV float bf2f(unsigned short s) {
  union { unsigned u; float f; } v; v.u = ((unsigned)s) << 16;
  return v.f;
}

DEV void mfma16(f32x4& d, const s16x8& a, const s16x8& b) {
  d = __builtin_amdgcn_mfma_f32_16x16x32_bf16(
      __builtin_bit_cast(bf16x8, a), __builtin_bit_cast(bf16x8, b), d, 0, 0, 0);
}

typedef const unsigned int gu32 __attribute__((address_space(1)));
typedef unsigned int lu32 __attribute__((address_space(3)));
DEV void gl_lds16(const void* g, void* l) {
  __builtin_amdgcn_global_load_lds((gu32*)g, (lu32*)l, 16, 0, 0);
}

// ---------------------------------------------------------------------------
// Weight transpose fp32 (K x N, submatrix) -> bf16 (N x Kp) at dst rowOff
// ---------------------------------------------------------------------------
__global__ void transpose_w(const float* __restrict__ src, int srcLd, int K,
                            int colOff, int nCols,
                            unsigned short* __restrict__ dst, int dstLd, int rowOff)
{
  __shared__ float tile[32][33];
  int tx = threadIdx.x & 31, ty = threadIdx.x >> 5;
  int k0 = blockIdx.y * 32, n0 = blockIdx.x * 32;
#pragma unroll
  for (int r = 0; r < 4; ++r) {
    int kk = k0 + ty + r * 8;
    int nn = n0 + tx;
    if (kk < K && nn < nCols) tile[ty + r * 8][tx] = src[(size_t)kk * srcLd + colOff + nn];
  }
  __syncthreads();
#pragma unroll
  for (int r = 0; r < 4; ++r) {
    int nn = n0 + ty + r * 8;
    int kk = k0 + tx;
    if (nn < nCols && kk < K)
      dst[(size_t)(rowOff + nn) * dstLd + kk] = f2bf(tile[tx][ty + r * 8]);
  }
}

// ---------------------------------------------------------------------------
__global__ void biaspad_kernel(const float* __restrict__ b, float* __restrict__ out)
{
  int n = blockIdx.x * 256 + threadIdx.x;
  if (n >= 5632) return;
  float v = 0.f;
  if (n < 2730) v = b[n];
  else if (n >= 2816 && n < 5546) v = b[2730 + n - 2816];
  out[n] = v;
}

// ---------------------------------------------------------------------------
// ada = silu(c) @ adaLN_w + adaLN_b    (B=4, K=1024, N=6144)
// ---------------------------------------------------------------------------
__global__ void ada_kernel(const float* __restrict__ c, const float* __restrict__ w,
                           const float* __restrict__ b, float* __restrict__ ada)
{
  __shared__ float cs[1024];
  int bb = blockIdx.y;
  int j = blockIdx.x * 256 + threadIdx.x;
  for (int i = threadIdx.x; i < 1024; i += 256) {
    float v = c[bb * 1024 + i];
    cs[i] = v / (1.f + __expf(-v));
  }
  __syncthreads();
  float acc = b[j];
  for (int k = 0; k < 1024; ++k) acc = fmaf(cs[k], w[(size_t)k * 6144 + j], acc);
  ada[bb * 6144 + j] = acc;
}

// ---------------------------------------------------------------------------
// xm = ((x * rsqrt(mean(x^2)+eps)) * nscale) * (1+sc) + sh   -> bf16
// ---------------------------------------------------------------------------
__global__ void rmsmod_kernel(const float* __restrict__ x, const float* __restrict__ nsc,
                              const float* __restrict__ ada, int shOff, int scOff,
                              unsigned short* __restrict__ out)
{
  int row = blockIdx.x;
  int t = threadIdx.x;
  const f32x4* xr = (const f32x4*)(x + (size_t)row * 1024);
  f32x4 v = xr[t];
  float ss = v[0]*v[0] + v[1]*v[1] + v[2]*v[2] + v[3]*v[3];
#pragma unroll
  for (int off = 32; off >= 1; off >>= 1) ss += __shfl_xor(ss, off, 64);
  __shared__ float red[4];
  int lane = t & 63, wv = t >> 6;
  if (lane == 0) red[wv] = ss;
  __syncthreads();
  float tot = red[0] + red[1] + red[2] + red[3];
  float rms = rsqrtf(tot * (1.f / 1024.f) + 1e-6f);
  int bb = row >> 12;
  const float* ab = ada + bb * 6144;
  s16x4 o;
#pragma unroll
  for (int i = 0; i < 4; ++i) {
    int col = t * 4 + i;
    float xn = v[i] * rms * nsc[col];
    float val = xn * (1.f + ab[scOff + col]) + ab[shOff + col];
    o[i] = (short)f2bf(val);
  }
  *(s16x4*)(out + (size_t)row * 1024 + t * 4) = o;
}

// ---------------------------------------------------------------------------
// GEMM: C = A(bf16 MxK, row stride lda) * BT(bf16 NxK)^T + epilogue.
// 128x128 tile, BK=32, 4 waves (2x2 of 64x64), global_load_lds w16 with
// pre-swizzled source, XOR swizzle chunk^((row>>1)&3) inside 64B LDS rows.
// MODE 0/2: bf16 store + bias
// MODE 1/3: f32 store res + gate*(v+b)   (gate row = mOff + local row)
// ---------------------------------------------------------------------------
template<int MODE>
__global__ void gemm128(const unsigned short* __restrict__ A, int lda,
                        const unsigned short* __restrict__ BT,
                        int N, int K,
                        const float* __restrict__ bias,
                        void* __restrict__ Cout,
                        const float* __restrict__ res,
                        const float* __restrict__ ada, int gateOff, int mOff)
{
  __shared__ __align__(16) unsigned short As[128 * 32];
  __shared__ __align__(16) unsigned short Bs[128 * 32];

  const int tid = threadIdx.x;
  const int lane = tid & 63;
  const int wv = tid >> 6;
  const int wr = wv >> 1, wc = wv & 1;
  const int g = lane >> 4, r16 = lane & 15;
  const int m0 = blockIdx.y * 128, n0 = blockIdx.x * 128;

  const int c0 = tid, c1 = 256 + tid;
  const int ra0 = c0 >> 2, ra1 = c1 >> 2;
  const int k0 = ((c0 & 3) ^ ((ra0 >> 1) & 3)) * 8;
  const int k1 = ((c1 & 3) ^ ((ra1 >> 1) & 3)) * 8;
  const unsigned short* ga0 = A + (size_t)(m0 + ra0) * lda + k0;
  const unsigned short* ga1 = A + (size_t)(m0 + ra1) * lda + k1;
  const unsigned short* gb0 = BT + (size_t)(n0 + ra0) * K + k0;
  const unsigned short* gb1 = BT + (size_t)(n0 + ra1) * K + k1;
  unsigned short* la0 = As + c0 * 8;
  unsigned short* la1 = As + c1 * 8;
  unsigned short* lb0 = Bs + c0 * 8;
  unsigned short* lb1 = Bs + c1 * 8;

  f32x4 acc[4][4];
#pragma unroll
  for (int m = 0; m < 4; ++m)
#pragma unroll
    for (int n = 0; n < 4; ++n) { acc[m][n][0]=0.f; acc[m][n][1]=0.f; acc[m][n][2]=0.f; acc[m][n][3]=0.f; }

  int aoff[4], boff[4];
#pragma unroll
  for (int m = 0; m < 4; ++m) {
    int rl = wr * 64 + m * 16 + r16;
    aoff[m] = rl * 32 + (g ^ ((rl >> 1) & 3)) * 8;
    int rb = wc * 64 + m * 16 + r16;
    boff[m] = rb * 32 + (g ^ ((rb >> 1) & 3)) * 8;
  }

  const int nk = K >> 5;
  for (int kt = 0; kt < nk; ++kt) {
    __syncthreads();
    const int ko = kt * 32;
    gl_lds16(ga0 + ko, la0);
    gl_lds16(ga1 + ko, la1);
    gl_lds16(gb0 + ko, lb0);
    gl_lds16(gb1 + ko, lb1);
    __syncthreads();
    s16x8 af[4], bf[4];
#pragma unroll
    for (int m = 0; m < 4; ++m) af[m] = *(const s16x8*)(As + aoff[m]);
#pragma unroll
    for (int n = 0; n < 4; ++n) bf[n] = *(const s16x8*)(Bs + boff[n]);
#pragma unroll
    for (int m = 0; m < 4; ++m)
#pragma unroll
      for (int n = 0; n < 4; ++n) mfma16(acc[m][n], af[m], bf[n]);
  }

#pragma unroll
  for (int m = 0; m < 4; ++m) {
#pragma unroll
    for (int n = 0; n < 4; ++n) {
#pragma unroll
      for (int r = 0; r < 4; ++r) {
        int rg = m0 + wr * 64 + m * 16 + g * 4 + r;
        int cg = n0 + wc * 64 + n * 16 + r16;
        float v = acc[m][n][r] + bias[cg];
        size_t idx = (size_t)rg * N + cg;
        if (MODE == 0 || MODE == 2) {
          ((unsigned short*)Cout)[idx] = f2bf(v);
        } else {
          int bb = (mOff + rg) >> 12;
          float gate = ada[bb * 6144 + gateOff + cg];
          ((float*)Cout)[idx] = res[idx] + gate * v;
        }
      }
    }
  }
}

// ---------------------------------------------------------------------------
// V transpose: qkv v-part (per window/head 256j x 64d) -> vT[pair][64d][256j]
// chunked: grid = 16*windows_in_chunk
// ---------------------------------------------------------------------------
__global__ void vtrans_kernel(const unsigned short* __restrict__ qkv,
                              unsigned short* __restrict__ vT)
{
  __shared__ unsigned short tl[64][72];
  int pidx = blockIdx.x;
  int w = pidx >> 4, h = pidx & 15;
  int t = threadIdx.x;
  for (int jb = 0; jb < 4; ++jb) {
    int jl = t >> 2, dc = t & 3;
    const unsigned short* srcp =
        qkv + (size_t)(w * 256 + jb * 64 + jl) * 3072 + 2048 + h * 64 + dc * 16;
    s16x8 v0 = *(const s16x8*)(srcp);
    s16x8 v1 = *(const s16x8*)(srcp + 8);
    if (jb) __syncthreads();
    *(s16x8*)(&tl[jl][dc * 16]) = v0;
    *(s16x8*)(&tl[jl][dc * 16 + 8]) = v1;
    __syncthreads();
    int dl = t >> 2, jc = t & 3;
    s16x8 o0, o1;
#pragma unroll
    for (int i = 0; i < 8; ++i) {
      o0[i] = (short)tl[jc * 16 + i][dl];
      o1[i] = (short)tl[jc * 16 + 8 + i][dl];
    }
    unsigned short* dstp = vT + (size_t)pidx * (64 * 256) + (size_t)dl * 256 + jb * 64 + jc * 16;
    *(s16x8*)(dstp) = o0;
    *(s16x8*)(dstp + 8) = o1;
  }
}

// ---------------------------------------------------------------------------
// Fused windowed attention, one block per (window, head). 4 waves x 64 q-rows.
// ---------------------------------------------------------------------------
__global__ __launch_bounds__(256, 1) void attn_kernel(
    const unsigned short* __restrict__ qkv,
    const unsigned short* __restrict__ vT,
    unsigned short* __restrict__ attnout)
{
  __shared__ __align__(16) unsigned short Kl[256 * 64];
  __shared__ __align__(16) unsigned short Vl[64 * 256];
  __shared__ __align__(16) unsigned short Pl[4][64 * 88];

  const int tid = threadIdx.x;
  const int lane = tid & 63;
  const int wv = tid >> 6;
  const int g = lane >> 4, r16 = lane & 15;
  const int p = blockIdx.x;
  const int w = p >> 4, h = p & 15;
  const float hh = (float)h;
  const float F = 0.4152410118609203f; // log2(10000)/32

  // ---- stage K with rope (swizzled chunks c ^ (j&7)) ----
#pragma unroll
  for (int it = 0; it < 4; ++it) {
    int idx = it * 256 + tid;
    int j = idx >> 2;
    int c = idx & 3;
    const unsigned short* kg = qkv + (size_t)(w * 256 + j) * 3072 + 1024 + h * 64;
    s16x8 lo = *(const s16x8*)(kg + c * 8);
    s16x8 hi = *(const s16x8*)(kg + 32 + c * 8);
    s16x8 plo, phi;
#pragma unroll
    for (int i2 = 0; i2 < 4; ++i2) {
      float f1 = exp2f(-(float)(c * 4 + i2) * F);
      float f2 = exp2f(-(float)(16 + c * 4 + i2) * F);
      float s1, c1s, s2, c2s;
      sincosf(hh * f1, &s1, &c1s);
      sincosf(hh * f2, &s2, &c2s);
#pragma unroll
      for (int u = 0; u < 2; ++u) {
        int i = i2 * 2 + u;
        float a = bf2f((unsigned short)lo[i]);
        float b = bf2f((unsigned short)hi[i]);
        plo[i] = (short)f2bf(a * c1s - b * s1);
        phi[i] = (short)f2bf(b * c2s + a * s2);
      }
    }
    int swzL = c ^ (j & 7);
    int swzH = (c + 4) ^ (j & 7);
    *(s16x8*)(Kl + j * 64 + swzL * 8) = plo;
    *(s16x8*)(Kl + j * 64 + swzH * 8) = phi;
  }
  // ---- stage V^T (swizzle low 3 bits of 16B-chunk with d&7) ----
  {
    const unsigned short* vg = vT + (size_t)p * (64 * 256);
#pragma unroll
    for (int it = 0; it < 8; ++it) {
      int idx = it * 256 + tid;
      int d = idx >> 5;
      int c = idx & 31;
      s16x8 val = *(const s16x8*)(vg + d * 256 + c * 8);
      int cs = (c & ~7) | ((c ^ d) & 7);
      *(s16x8*)(Vl + d * 256 + cs * 8) = val;
    }
  }

  // ---- Q load + rope into frags ----
  s16x8 qa[4][2];
  {
    float cs0[4], sn0[4], cs1[4], sn1[4];
#pragma unroll
    for (int i2 = 0; i2 < 4; ++i2) {
      float f1 = exp2f(-(float)(g * 4 + i2) * F);
      float f2 = exp2f(-(float)(16 + g * 4 + i2) * F);
      sincosf(hh * f1, &sn0[i2], &cs0[i2]);
      sincosf(hh * f2, &sn1[i2], &cs1[i2]);
    }
#pragma unroll
    for (int m = 0; m < 4; ++m) {
      const unsigned short* qg =
          qkv + (size_t)(w * 256 + wv * 64 + m * 16 + r16) * 3072 + h * 64;
      s16x8 lo = *(const s16x8*)(qg + g * 8);
      s16x8 hi = *(const s16x8*)(qg + 32 + g * 8);
      s16x8 plo, phi;
#pragma unroll
      for (int i = 0; i < 8; ++i) {
        int i2 = i >> 1;
        float a = bf2f((unsigned short)lo[i]);
        float b = bf2f((unsigned short)hi[i]);
        plo[i] = (short)f2bf(a * cs0[i2] - b * sn0[i2]);
        phi[i] = (short)f2bf(b * cs1[i2] + a * sn1[i2]);
      }
      qa[m][0] = plo;
      qa[m][1] = phi;
    }
  }

  __syncthreads();

  f32x4 accO[4][4];
  float Mx[4][4], Ls[4][4];
#pragma unroll
  for (int m = 0; m < 4; ++m)
#pragma unroll
    for (int r = 0; r < 4; ++r) {
      Mx[m][r] = -3.0e38f;
      Ls[m][r] = 0.f;
      accO[m][r][0]=0.f; accO[m][r][1]=0.f; accO[m][r][2]=0.f; accO[m][r][3]=0.f;
    }
  unsigned short* Pw = &Pl[wv][0];
  const float zs = 0.125f * 1.44269504f;

  for (int kb = 0; kb < 4; ++kb) {
    f32x4 s[4][4];
#pragma unroll
    for (int m = 0; m < 4; ++m)
#pragma unroll
      for (int jt = 0; jt < 4; ++jt) { s[m][jt][0]=0.f; s[m][jt][1]=0.f; s[m][jt][2]=0.f; s[m][jt][3]=0.f; }

#pragma unroll
    for (int jt = 0; jt < 4; ++jt) {
      int j = kb * 64 + jt * 16 + r16;
      s16x8 bk0 = *(const s16x8*)(Kl + j * 64 + ((g ^ (j & 7)) * 8));
      s16x8 bk1 = *(const s16x8*)(Kl + j * 64 + (((4 + g) ^ (j & 7)) * 8));
#pragma unroll
      for (int m = 0; m < 4; ++m) {
        mfma16(s[m][jt], qa[m][0], bk0);
        mfma16(s[m][jt], qa[m][1], bk1);
      }
    }

#pragma unroll
    for (int m = 0; m < 4; ++m) {
#pragma unroll
      for (int r = 0; r < 4; ++r) {
        float mx = fmaxf(fmaxf(s[m][0][r], s[m][1][r]), fmaxf(s[m][2][r], s[m][3][r]));
        mx = fmaxf(mx, __shfl_xor(mx, 1, 16));
        mx = fmaxf(mx, __shfl_xor(mx, 2, 16));
        mx = fmaxf(mx, __shfl_xor(mx, 4, 16));
        mx = fmaxf(mx, __shfl_xor(mx, 8, 16));
        float Mn = fmaxf(Mx[m][r], mx * zs);
        float fsc = exp2f(Mx[m][r] - Mn);
        Mx[m][r] = Mn;
        float ps = 0.f;
#pragma unroll
        for (int jt = 0; jt < 4; ++jt) {
          float pv = exp2f(s[m][jt][r] * zs - Mn);
          s[m][jt][r] = pv;
          ps += pv;
        }
        ps += __shfl_xor(ps, 1, 16);
        ps += __shfl_xor(ps, 2, 16);
        ps += __shfl_xor(ps, 4, 16);
        ps += __shfl_xor(ps, 8, 16);
        Ls[m][r] = Ls[m][r] * fsc + ps;
#pragma unroll
        for (int dt = 0; dt < 4; ++dt) accO[m][dt][r] *= fsc;
      }
    }

    // write P (bf16) into per-wave LDS, layout [64 q][88 j]
#pragma unroll
    for (int m = 0; m < 4; ++m)
#pragma unroll
      for (int jt = 0; jt < 4; ++jt)
#pragma unroll
        for (int r = 0; r < 4; ++r) {
          int q = m * 16 + g * 4 + r;
          int jj = jt * 16 + r16;
          Pw[q * 88 + jj] = f2bf(s[m][jt][r]);
        }
    asm volatile("s_waitcnt lgkmcnt(0)" ::: "memory");
    __builtin_amdgcn_sched_barrier(0);

    // PV
#pragma unroll
    for (int c = 0; c < 2; ++c) {
      s16x8 pa[4];
#pragma unroll
      for (int m = 0; m < 4; ++m)
        pa[m] = *(const s16x8*)(Pw + (m * 16 + r16) * 88 + c * 32 + g * 8);
#pragma unroll
      for (int dt = 0; dt < 4; ++dt) {
        int d = dt * 16 + r16;
        int cch = kb * 8 + c * 4 + g;
        int csz = (cch & ~7) | ((cch ^ d) & 7);
        s16x8 vb = *(const s16x8*)(Vl + d * 256 + csz * 8);
#pragma unroll
        for (int m = 0; m < 4; ++m) mfma16(accO[m][dt], pa[m], vb);
      }
    }
    asm volatile("s_waitcnt lgkmcnt(0)" ::: "memory");
    __builtin_amdgcn_sched_barrier(0);
  }

#pragma unroll
  for (int m = 0; m < 4; ++m)
#pragma unroll
    for (int dt = 0; dt < 4; ++dt)
#pragma unroll
      for (int r = 0; r < 4; ++r) {
        int rg = w * 256 + wv * 64 + m * 16 + g * 4 + r;
        int cg = h * 64 + dt * 16 + r16;
        float val = accO[m][dt][r] / Ls[m][r];
        attnout[(size_t)rg * 1024 + cg] = f2bf(val);
      }
}

// ---------------------------------------------------------------------------
// In-place h = silu(w1)*w2: row has 5632 cols (w1: 0..2815, w2: 2816..5631);
// result written into cols 0..2815 of the same row.
// ---------------------------------------------------------------------------
__global__ void silu_mul_kernel(unsigned short* __restrict__ w12o)
{
  int row = blockIdx.x;
  unsigned short* r1 = w12o + (size_t)row * 5632;
  const unsigned short* r2 = r1 + 2816;
  for (int cidx = threadIdx.x; cidx < 352; cidx += 256) {
    s16x8 a = *(const s16x8*)(r1 + cidx * 8);
    s16x8 b = *(const s16x8*)(r2 + cidx * 8);
    s16x8 o;
#pragma unroll
    for (int i = 0; i < 8; ++i) {
      float av = bf2f((unsigned short)a[i]);
      float bv = bf2f((unsigned short)b[i]);
      float sv = av / (1.f + __expf(-av));
      o[i] = (short)f2bf(sv * bv);
    }
    *(s16x8*)(r1 + cidx * 8) = o;
  }
}

// ---------------------------------------------------------------------------
extern "C" void kernel_launch(void* const* d_in, const int* in_sizes, int n_in,
                              void* d_out, int out_size, void* d_ws, size_t ws_size,
                              hipStream_t stream)
{
  const float* x    = (const float*)d_in[0];
  const float* c    = (const float*)d_in[1];
  const float* n1s  = (const float*)d_in[2];
  const float* n2s  = (const float*)d_in[3];
  const float* adaW = (const float*)d_in[4];
  const float* adaB = (const float*)d_in[5];
  const float* qkvW = (const float*)d_in[6];
  const float* qkvB = (const float*)d_in[7];
  const float* outW = (const float*)d_in[8];
  const float* outB = (const float*)d_in[9];
  const float* w12W = (const float*)d_in[10];
  const float* w12B = (const float*)d_in[11];
  const float* w3W  = (const float*)d_in[12];
  const float* w3B  = (const float*)d_in[13];

  char* ws = (char*)d_ws;
  // Peak scratch demand: 59,365,376 + 92,274,688 = 151,640,064 B (~144.6 MiB)
  constexpr size_t OFF_ADA  = 0;                          //    98,304
  constexpr size_t OFF_QKVT = 98304;                      // 6,291,456
  constexpr size_t OFF_OUTT = OFF_QKVT + 6291456;         // 2,097,152
  constexpr size_t OFF_W12T = OFF_OUTT + 2097152;         // 11,534,336
  constexpr size_t OFF_W3T  = OFF_W12T + 11534336;        // 5,767,168
  constexpr size_t OFF_BPAD = OFF_W3T + 5767168;          //    22,528
  constexpr size_t OFF_XM   = OFF_BPAD + 22528;           // 33,554,432 (also attno-alias? no: xm)
  constexpr size_t OFF_BIG  = OFF_XM + 33554432;          // = 59,365,376
  // BIG region, attn phase (per 8192-row chunk):
  constexpr size_t OFF_QKVC = OFF_BIG;                    // 50,331,648
  constexpr size_t OFF_VTC  = OFF_BIG + 50331648;         // 16,777,216
  constexpr size_t OFF_ATTC = OFF_BIG + 67108864;         // 16,777,216
  // BIG region, MLP phase (per 8192-row chunk):
  constexpr size_t OFF_W12O = OFF_BIG;                    // 92,274,688

  float* ada            = (float*)(ws + OFF_ADA);
  unsigned short* qkvT  = (unsigned short*)(ws + OFF_QKVT);
  unsigned short* outT  = (unsigned short*)(ws + OFF_OUTT);
  unsigned short* w12T  = (unsigned short*)(ws + OFF_W12T);
  unsigned short* w3T   = (unsigned short*)(ws + OFF_W3T);
  float* biasPad        = (float*)(ws + OFF_BPAD);
  unsigned short* xm    = (unsigned short*)(ws + OFF_XM);
  unsigned short* qkvbC = (unsigned short*)(ws + OFF_QKVC);
  unsigned short* vTbC  = (unsigned short*)(ws + OFF_VTC);
  unsigned short* attnC = (unsigned short*)(ws + OFF_ATTC);
  unsigned short* w12oC = (unsigned short*)(ws + OFF_W12O);
  float* x2             = (float*)d_out;   // d_out doubles as post-attn state

  // --- prep: weights to bf16, transposed/padded ---
  hipMemsetAsync(w12T, 0, 11534336, stream);
  hipMemsetAsync(w3T, 0, 5767168, stream);
  transpose_w<<<dim3(96, 32), 256, 0, stream>>>(qkvW, 3072, 1024, 0, 3072, qkvT, 1024, 0);
  transpose_w<<<dim3(32, 32), 256, 0, stream>>>(outW, 1024, 1024, 0, 1024, outT, 1024, 0);
  transpose_w<<<dim3(86, 32), 256, 0, stream>>>(w12W, 5460, 1024, 0, 2730, w12T, 1024, 0);
  transpose_w<<<dim3(86, 32), 256, 0, stream>>>(w12W, 5460, 1024, 2730, 2730, w12T, 1024, 2816);
  transpose_w<<<dim3(32, 86), 256, 0, stream>>>(w3W, 1024, 2730, 0, 1024, w3T, 2816, 0);
  biaspad_kernel<<<22, 256, 0, stream>>>(w12B, biasPad);
  ada_kernel<<<dim3(24, 4), 256, 0, stream>>>(c, adaW, adaB, ada);

  // --- attention branch (2 chunks of 8192 rows = 32 windows) ---
  rmsmod_kernel<<<16384, 256, 0, stream>>>(x, n1s, ada, 0, 1024, xm);
  for (int ch = 0; ch < 2; ++ch) {
    const size_t ro = (size_t)ch * 8192;
    gemm128<0><<<dim3(24, 64), 256, 0, stream>>>(
        xm + ro * 1024, 1024, qkvT, 3072, 1024, qkvB, qkvbC, nullptr, nullptr, 0, 0);
    vtrans_kernel<<<512, 256, 0, stream>>>(qkvbC, vTbC);
    attn_kernel<<<512, 256, 0, stream>>>(qkvbC, vTbC, attnC);
    gemm128<1><<<dim3(8, 64), 256, 0, stream>>>(
        attnC, 1024, outT, 1024, 1024, outB, x2 + ro * 1024, x + ro * 1024,
        ada, 2048, (int)ro);
  }

  // --- MLP branch (2 chunks of 8192 rows) ---
  rmsmod_kernel<<<16384, 256, 0, stream>>>(x2, n2s, ada, 3072, 4096, xm);
  for (int ch = 0; ch < 2; ++ch) {
    const size_t ro = (size_t)ch * 8192;
    gemm128<2><<<dim3(44, 64), 256, 0, stream>>>(
        xm + ro * 1024, 1024, w12T, 5632, 1024, biasPad, w12oC, nullptr, nullptr, 0, 0);
    silu_mul_kernel<<<8192, 256, 0, stream>>>(w12oC);
    gemm128<3><<<dim3(8, 64), 256, 0, stream>>>(
        w12oC, 5632, w3T, 1024, 2816, w3B, x2 + ro * 1024, x2 + ro * 1024,
        ada, 5120, (int)ro);
  }
}

// Round 3
// 900.912 us; speedup vs baseline: 1.0274x; 1.0274x over previous
//
#include <hip/hip_runtime.h>
#include <hip/hip_bf16.h>
#include <cstdint>
#include <cstddef>

#define DEV __device__ __forceinline__

typedef float f32x4 __attribute__((ext_vector_type(4)));
typedef short s16x8 __attribute__((ext_vector_type(8)));
typedef short s16x4 __attribute__((ext_vector_type(4)));
typedef __bf16 bf16x8 __attribute__((ext_vector_type(8)));

DEV unsigned short f2bf(float f) {
  union { float f; unsigned u; } v; v.f = f;
  return (unsigned short)((v.u + 0x7FFFu + ((v.u >> 16) & 1u)) >> 16);
}
DEV float bf2f(unsigned short s) {
  union { unsigned u; float f; } v; v.u = ((unsigned)s) << 16;
  return v.f;
}

DEV void mfma16(f32x4& d, const s16x8& a, const s16x8& b) {
  d = __builtin_amdgcn_mfma_f32_16x16x32_bf16(
      __builtin_bit_cast(bf16x8, a), __builtin_bit_cast(bf16x8, b), d, 0, 0, 0);
}

typedef const unsigned int gu32 __attribute__((address_space(1)));
typedef unsigned int lu32 __attribute__((address_space(3)));
DEV void gl_lds16(const void* g, void* l) {
  __builtin_amdgcn_global_load_lds((gu32*)g, (lu32*)l, 16, 0, 0);
}

// ---------------------------------------------------------------------------
// Weight transpose fp32 (K x N, submatrix) -> bf16 (N x Kp) at dst rowOff
// ---------------------------------------------------------------------------
__global__ void transpose_w(const float* __restrict__ src, int srcLd, int K,
                            int colOff, int nCols,
                            unsigned short* __restrict__ dst, int dstLd, int rowOff)
{
  __shared__ float tile[32][33];
  int tx = threadIdx.x & 31, ty = threadIdx.x >> 5;
  int k0 = blockIdx.y * 32, n0 = blockIdx.x * 32;
#pragma unroll
  for (int r = 0; r < 4; ++r) {
    int kk = k0 + ty + r * 8;
    int nn = n0 + tx;
    if (kk < K && nn < nCols) tile[ty + r * 8][tx] = src[(size_t)kk * srcLd + colOff + nn];
  }
  __syncthreads();
#pragma unroll
  for (int r = 0; r < 4; ++r) {
    int nn = n0 + ty + r * 8;
    int kk = k0 + tx;
    if (nn < nCols && kk < K)
      dst[(size_t)(rowOff + nn) * dstLd + kk] = f2bf(tile[tx][ty + r * 8]);
  }
}

// ---------------------------------------------------------------------------
__global__ void biaspad_kernel(const float* __restrict__ b, float* __restrict__ out)
{
  int n = blockIdx.x * 256 + threadIdx.x;
  if (n >= 5632) return;
  float v = 0.f;
  if (n < 2730) v = b[n];
  else if (n >= 2816 && n < 5546) v = b[2730 + n - 2816];
  out[n] = v;
}

// ---------------------------------------------------------------------------
// ada = silu(c) @ adaLN_w + adaLN_b    (B=4, K=1024, N=6144)
// ---------------------------------------------------------------------------
__global__ void ada_kernel(const float* __restrict__ c, const float* __restrict__ w,
                           const float* __restrict__ b, float* __restrict__ ada)
{
  __shared__ float cs[1024];
  int bb = blockIdx.y;
  int j = blockIdx.x * 256 + threadIdx.x;
  for (int i = threadIdx.x; i < 1024; i += 256) {
    float v = c[bb * 1024 + i];
    cs[i] = v / (1.f + __expf(-v));
  }
  __syncthreads();
  float acc = b[j];
  for (int k = 0; k < 1024; ++k) acc = fmaf(cs[k], w[(size_t)k * 6144 + j], acc);
  ada[bb * 6144 + j] = acc;
}

// ---------------------------------------------------------------------------
// xm = ((x * rsqrt(mean(x^2)+eps)) * nscale) * (1+sc) + sh   -> bf16
// ---------------------------------------------------------------------------
__global__ void rmsmod_kernel(const float* __restrict__ x, const float* __restrict__ nsc,
                              const float* __restrict__ ada, int shOff, int scOff,
                              unsigned short* __restrict__ out)
{
  int row = blockIdx.x;
  int t = threadIdx.x;
  const f32x4* xr = (const f32x4*)(x + (size_t)row * 1024);
  f32x4 v = xr[t];
  float ss = v[0]*v[0] + v[1]*v[1] + v[2]*v[2] + v[3]*v[3];
#pragma unroll
  for (int off = 32; off >= 1; off >>= 1) ss += __shfl_xor(ss, off, 64);
  __shared__ float red[4];
  int lane = t & 63, wv = t >> 6;
  if (lane == 0) red[wv] = ss;
  __syncthreads();
  float tot = red[0] + red[1] + red[2] + red[3];
  float rms = rsqrtf(tot * (1.f / 1024.f) + 1e-6f);
  int bb = row >> 12;
  const float* ab = ada + bb * 6144;
  s16x4 o;
#pragma unroll
  for (int i = 0; i < 4; ++i) {
    int col = t * 4 + i;
    float xn = v[i] * rms * nsc[col];
    float val = xn * (1.f + ab[scOff + col]) + ab[shOff + col];
    o[i] = (short)f2bf(val);
  }
  *(s16x4*)(out + (size_t)row * 1024 + t * 4) = o;
}

// ---------------------------------------------------------------------------
// gemm256: C = A(bf16 MxK, stride lda) * BT(bf16 NxK, stride ldb)^T + bias,
// bf16 out. 256x256 tile, BK=64, 8 waves (2Mx4N), 8-phase schedule:
// per K-tile 4 quadrant-phases, 1 half-tile staged per phase via
// global_load_lds w16 (pre-swizzled source), counted vmcnt(2) per tile,
// lgkmcnt(0)+sched_barrier before MFMA clusters, setprio around MFMA.
// LDS: A[2][256][64] + B[2][256][64] bf16 = 128 KiB (1 block/CU).
// Requires: M%256==0, N%256==0, K%64==0, K/64 >= 2, grid multiple of 8.
// ---------------------------------------------------------------------------
__global__ __launch_bounds__(512, 2) void gemm256(
    const unsigned short* __restrict__ A, int lda,
    const unsigned short* __restrict__ BT, int ldb,
    int N, int K,
    const float* __restrict__ bias,
    unsigned short* __restrict__ Cout)
{
  __shared__ __align__(16) char lds[131072];

  const int tid = threadIdx.x;
  const int lane = tid & 63;
  const int wv = tid >> 6;
  const int wr = wv >> 2;        // 0..1  (M half)
  const int wn = wv & 3;         // 0..3  (N quarter)
  const int g = lane >> 4, r16 = lane & 15;

  // XCD-aware bijective block swizzle (grid % 8 == 0 guaranteed by caller)
  const int nwg = gridDim.x * gridDim.y;
  const int bid = blockIdx.x + gridDim.x * blockIdx.y;
  const int qq = nwg >> 3;
  const int swz = (bid & 7) * qq + (bid >> 3);
  const int m0 = (swz / gridDim.x) * 256;
  const int n0 = (swz % gridDim.x) * 256;

  const int nkt = K >> 6;
  const int nhalves = nkt << 2;

  // staging one half-tile h: tile t=h>>2, slot s=h&3 (0:Bh0 1:Bh1 2:Ah0 3:Ah1)
  auto stage_half = [&](int h) {
    if (h >= nhalves) return;
    const int t = h >> 2, s = h & 3, bs = t & 1;
#pragma unroll
    for (int it = 0; it < 2; ++it) {
      const int cidx = it * 512 + tid;
      const int rl = cidx >> 3, cc = cidx & 7;
      if (s >= 2) {
        const int row = (s - 2) * 128 + rl;
        const unsigned short* src =
            A + (size_t)(m0 + row) * lda + t * 64 + ((cc ^ (row & 7)) << 3);
        gl_lds16(src, lds + bs * 32768 + (s - 2) * 16384 + cidx * 16);
      } else {
        const int row = s * 128 + rl;
        const unsigned short* src =
            BT + (size_t)(n0 + row) * ldb + t * 64 + ((cc ^ (row & 7)) << 3);
        gl_lds16(src, lds + 65536 + bs * 32768 + s * 16384 + cidx * 16);
      }
    }
  };

  f32x4 acc[8][4];
#pragma unroll
  for (int m = 0; m < 8; ++m)
#pragma unroll
    for (int n = 0; n < 4; ++n) { acc[m][n][0]=0.f; acc[m][n][1]=0.f; acc[m][n][2]=0.f; acc[m][n][3]=0.f; }

  // per-thread ds_read byte offsets (within a buffer)
  int swzk[2];
#pragma unroll
  for (int ks = 0; ks < 2; ++ks) swzk[ks] = (((ks << 2) + g) ^ (r16 & 7)) << 4;
  int arow0[4], arow1[4], brow0[2], brow1[2];
#pragma unroll
  for (int m = 0; m < 4; ++m) {
    arow0[m] = (wr * 128 + m * 16 + r16) * 128;
    arow1[m] = (wr * 128 + 64 + m * 16 + r16) * 128;
  }
#pragma unroll
  for (int n = 0; n < 2; ++n) {
    brow0[n] = 65536 + (wn * 64 + n * 16 + r16) * 128;
    brow1[n] = 65536 + (wn * 64 + 32 + n * 16 + r16) * 128;
  }

  // prologue: stage halves 0..4, wait tile 0 landed (leave newest half in flight)
  stage_half(0); stage_half(1); stage_half(2); stage_half(3); stage_half(4);
  asm volatile("s_waitcnt vmcnt(2)" ::: "memory");
  __builtin_amdgcn_s_barrier();

  s16x8 af[4][2], b0[2][2], b1[2][2];

  for (int kt = 0; kt < nkt; ++kt) {
    const int boff = (kt & 1) * 32768;
    // ---------------- phase 0: quadrant (mh0, nh0) ----------------
#pragma unroll
    for (int m = 0; m < 4; ++m)
#pragma unroll
      for (int ks = 0; ks < 2; ++ks)
        af[m][ks] = *(const s16x8*)(lds + boff + arow0[m] + swzk[ks]);
#pragma unroll
    for (int n = 0; n < 2; ++n)
#pragma unroll
      for (int ks = 0; ks < 2; ++ks)
        b0[n][ks] = *(const s16x8*)(lds + boff + brow0[n] + swzk[ks]);
    stage_half(4 * kt + 5);
    __builtin_amdgcn_sched_barrier(0);
    __builtin_amdgcn_s_barrier();
    asm volatile("s_waitcnt lgkmcnt(0)" ::: "memory");
    __builtin_amdgcn_sched_barrier(0);
    __builtin_amdgcn_s_setprio(1);
#pragma unroll
    for (int m = 0; m < 4; ++m)
#pragma unroll
      for (int n = 0; n < 2; ++n)
#pragma unroll
        for (int ks = 0; ks < 2; ++ks)
          mfma16(acc[m][n], af[m][ks], b0[n][ks]);
    __builtin_amdgcn_s_setprio(0);
    __builtin_amdgcn_sched_barrier(0);
    __builtin_amdgcn_s_barrier();
    // ---------------- phase 1: quadrant (mh0, nh1) ----------------
#pragma unroll
    for (int n = 0; n < 2; ++n)
#pragma unroll
      for (int ks = 0; ks < 2; ++ks)
        b1[n][ks] = *(const s16x8*)(lds + boff + brow1[n] + swzk[ks]);
    stage_half(4 * kt + 6);
    __builtin_amdgcn_sched_barrier(0);
    __builtin_amdgcn_s_barrier();
    asm volatile("s_waitcnt lgkmcnt(0)" ::: "memory");
    __builtin_amdgcn_sched_barrier(0);
    __builtin_amdgcn_s_setprio(1);
#pragma unroll
    for (int m = 0; m < 4; ++m)
#pragma unroll
      for (int n = 0; n < 2; ++n)
#pragma unroll
        for (int ks = 0; ks < 2; ++ks)
          mfma16(acc[m][2 + n], af[m][ks], b1[n][ks]);
    __builtin_amdgcn_s_setprio(0);
    __builtin_amdgcn_sched_barrier(0);
    __builtin_amdgcn_s_barrier();
    // ---------------- phase 2: quadrant (mh1, nh1) ----------------
#pragma unroll
    for (int m = 0; m < 4; ++m)
#pragma unroll
      for (int ks = 0; ks < 2; ++ks)
        af[m][ks] = *(const s16x8*)(lds + boff + arow1[m] + swzk[ks]);
    stage_half(4 * kt + 7);
    __builtin_amdgcn_sched_barrier(0);
    __builtin_amdgcn_s_barrier();
    asm volatile("s_waitcnt lgkmcnt(0)" ::: "memory");
    __builtin_amdgcn_sched_barrier(0);
    __builtin_amdgcn_s_setprio(1);
#pragma unroll
    for (int m = 0; m < 4; ++m)
#pragma unroll
      for (int n = 0; n < 2; ++n)
#pragma unroll
        for (int ks = 0; ks < 2; ++ks)
          mfma16(acc[4 + m][2 + n], af[m][ks], b1[n][ks]);
    __builtin_amdgcn_s_setprio(0);
    __builtin_amdgcn_sched_barrier(0);
    __builtin_amdgcn_s_barrier();
    // ---------------- phase 3: quadrant (mh1, nh0) ----------------
    stage_half(4 * kt + 8);
    __builtin_amdgcn_sched_barrier(0);
    __builtin_amdgcn_s_barrier();
    __builtin_amdgcn_s_setprio(1);
#pragma unroll
    for (int m = 0; m < 4; ++m)
#pragma unroll
      for (int n = 0; n < 2; ++n)
#pragma unroll
        for (int ks = 0; ks < 2; ++ks)
          mfma16(acc[4 + m][n], af[m][ks], b0[n][ks]);
    __builtin_amdgcn_s_setprio(0);
    __builtin_amdgcn_sched_barrier(0);
    if (kt + 2 < nkt) asm volatile("s_waitcnt vmcnt(2)" ::: "memory");
    else              asm volatile("s_waitcnt vmcnt(0)" ::: "memory");
    __builtin_amdgcn_s_barrier();
  }

  // epilogue: bias + bf16 store
#pragma unroll
  for (int fm = 0; fm < 8; ++fm) {
#pragma unroll
    for (int fn = 0; fn < 4; ++fn) {
#pragma unroll
      for (int r = 0; r < 4; ++r) {
        int rg = m0 + wr * 128 + fm * 16 + g * 4 + r;
        int cg = n0 + wn * 64 + fn * 16 + r16;
        Cout[(size_t)rg * N + cg] = f2bf(acc[fm][fn][r] + bias[cg]);
      }
    }
  }
}

// ---------------------------------------------------------------------------
// GEMM 128x128 (2-barrier structure) for the N=1024 GEMMs.
// MODE 1/3: f32 store res + gate*(v+b)
// ---------------------------------------------------------------------------
template<int MODE>
__global__ void gemm128(const unsigned short* __restrict__ A, int lda,
                        const unsigned short* __restrict__ BT,
                        int N, int K,
                        const float* __restrict__ bias,
                        void* __restrict__ Cout,
                        const float* __restrict__ res,
                        const float* __restrict__ ada, int gateOff, int mOff)
{
  __shared__ __align__(16) unsigned short As[128 * 32];
  __shared__ __align__(16) unsigned short Bs[128 * 32];

  const int tid = threadIdx.x;
  const int lane = tid & 63;
  const int wv = tid >> 6;
  const int wr = wv >> 1, wc = wv & 1;
  const int g = lane >> 4, r16 = lane & 15;
  const int m0 = blockIdx.y * 128, n0 = blockIdx.x * 128;

  const int c0 = tid, c1 = 256 + tid;
  const int ra0 = c0 >> 2, ra1 = c1 >> 2;
  const int k0 = ((c0 & 3) ^ ((ra0 >> 1) & 3)) * 8;
  const int k1 = ((c1 & 3) ^ ((ra1 >> 1) & 3)) * 8;
  const unsigned short* ga0 = A + (size_t)(m0 + ra0) * lda + k0;
  const unsigned short* ga1 = A + (size_t)(m0 + ra1) * lda + k1;
  const unsigned short* gb0 = BT + (size_t)(n0 + ra0) * K + k0;
  const unsigned short* gb1 = BT + (size_t)(n0 + ra1) * K + k1;
  unsigned short* la0 = As + c0 * 8;
  unsigned short* la1 = As + c1 * 8;
  unsigned short* lb0 = Bs + c0 * 8;
  unsigned short* lb1 = Bs + c1 * 8;

  f32x4 acc[4][4];
#pragma unroll
  for (int m = 0; m < 4; ++m)
#pragma unroll
    for (int n = 0; n < 4; ++n) { acc[m][n][0]=0.f; acc[m][n][1]=0.f; acc[m][n][2]=0.f; acc[m][n][3]=0.f; }

  int aoff[4], boff[4];
#pragma unroll
  for (int m = 0; m < 4; ++m) {
    int rl = wr * 64 + m * 16 + r16;
    aoff[m] = rl * 32 + (g ^ ((rl >> 1) & 3)) * 8;
    int rb = wc * 64 + m * 16 + r16;
    boff[m] = rb * 32 + (g ^ ((rb >> 1) & 3)) * 8;
  }

  const int nk = K >> 5;
  for (int kt = 0; kt < nk; ++kt) {
    __syncthreads();
    const int ko = kt * 32;
    gl_lds16(ga0 + ko, la0);
    gl_lds16(ga1 + ko, la1);
    gl_lds16(gb0 + ko, lb0);
    gl_lds16(gb1 + ko, lb1);
    __syncthreads();
    s16x8 af[4], bf[4];
#pragma unroll
    for (int m = 0; m < 4; ++m) af[m] = *(const s16x8*)(As + aoff[m]);
#pragma unroll
    for (int n = 0; n < 4; ++n) bf[n] = *(const s16x8*)(Bs + boff[n]);
#pragma unroll
    for (int m = 0; m < 4; ++m)
#pragma unroll
      for (int n = 0; n < 4; ++n) mfma16(acc[m][n], af[m], bf[n]);
  }

#pragma unroll
  for (int m = 0; m < 4; ++m) {
#pragma unroll
    for (int n = 0; n < 4; ++n) {
#pragma unroll
      for (int r = 0; r < 4; ++r) {
        int rg = m0 + wr * 64 + m * 16 + g * 4 + r;
        int cg = n0 + wc * 64 + n * 16 + r16;
        float v = acc[m][n][r] + bias[cg];
        size_t idx = (size_t)rg * N + cg;
        if (MODE == 0 || MODE == 2) {
          ((unsigned short*)Cout)[idx] = f2bf(v);
        } else {
          int bb = (mOff + rg) >> 12;
          float gate = ada[bb * 6144 + gateOff + cg];
          ((float*)Cout)[idx] = res[idx] + gate * v;
        }
      }
    }
  }
}

// ---------------------------------------------------------------------------
// V transpose: qkv v-part (per window/head 256j x 64d) -> vT[pair][64d][256j]
// ---------------------------------------------------------------------------
__global__ void vtrans_kernel(const unsigned short* __restrict__ qkv,
                              unsigned short* __restrict__ vT)
{
  __shared__ unsigned short tl[64][72];
  int pidx = blockIdx.x;
  int w = pidx >> 4, h = pidx & 15;
  int t = threadIdx.x;
  for (int jb = 0; jb < 4; ++jb) {
    int jl = t >> 2, dc = t & 3;
    const unsigned short* srcp =
        qkv + (size_t)(w * 256 + jb * 64 + jl) * 3072 + 2048 + h * 64 + dc * 16;
    s16x8 v0 = *(const s16x8*)(srcp);
    s16x8 v1 = *(const s16x8*)(srcp + 8);
    if (jb) __syncthreads();
    *(s16x8*)(&tl[jl][dc * 16]) = v0;
    *(s16x8*)(&tl[jl][dc * 16 + 8]) = v1;
    __syncthreads();
    int dl = t >> 2, jc = t & 3;
    s16x8 o0, o1;
#pragma unroll
    for (int i = 0; i < 8; ++i) {
      o0[i] = (short)tl[jc * 16 + i][dl];
      o1[i] = (short)tl[jc * 16 + 8 + i][dl];
    }
    unsigned short* dstp = vT + (size_t)pidx * (64 * 256) + (size_t)dl * 256 + jb * 64 + jc * 16;
    *(s16x8*)(dstp) = o0;
    *(s16x8*)(dstp + 8) = o1;
  }
}

// ---------------------------------------------------------------------------
// Fused windowed attention, one block per (window, head). 4 waves x 64 q-rows.
// ---------------------------------------------------------------------------
__global__ __launch_bounds__(256, 1) void attn_kernel(
    const unsigned short* __restrict__ qkv,
    const unsigned short* __restrict__ vT,
    unsigned short* __restrict__ attnout)
{
  __shared__ __align__(16) unsigned short Kl[256 * 64];
  __shared__ __align__(16) unsigned short Vl[64 * 256];
  __shared__ __align__(16) unsigned short Pl[4][64 * 88];

  const int tid = threadIdx.x;
  const int lane = tid & 63;
  const int wv = tid >> 6;
  const int g = lane >> 4, r16 = lane & 15;
  const int p = blockIdx.x;
  const int w = p >> 4, h = p & 15;
  const float hh = (float)h;
  const float F = 0.4152410118609203f; // log2(10000)/32

#pragma unroll
  for (int it = 0; it < 4; ++it) {
    int idx = it * 256 + tid;
    int j = idx >> 2;
    int c = idx & 3;
    const unsigned short* kg = qkv + (size_t)(w * 256 + j) * 3072 + 1024 + h * 64;
    s16x8 lo = *(const s16x8*)(kg + c * 8);
    s16x8 hi = *(const s16x8*)(kg + 32 + c * 8);
    s16x8 plo, phi;
#pragma unroll
    for (int i2 = 0; i2 < 4; ++i2) {
      float f1 = exp2f(-(float)(c * 4 + i2) * F);
      float f2 = exp2f(-(float)(16 + c * 4 + i2) * F);
      float s1, c1s, s2, c2s;
      sincosf(hh * f1, &s1, &c1s);
      sincosf(hh * f2, &s2, &c2s);
#pragma unroll
      for (int u = 0; u < 2; ++u) {
        int i = i2 * 2 + u;
        float a = bf2f((unsigned short)lo[i]);
        float b = bf2f((unsigned short)hi[i]);
        plo[i] = (short)f2bf(a * c1s - b * s1);
        phi[i] = (short)f2bf(b * c2s + a * s2);
      }
    }
    int swzL = c ^ (j & 7);
    int swzH = (c + 4) ^ (j & 7);
    *(s16x8*)(Kl + j * 64 + swzL * 8) = plo;
    *(s16x8*)(Kl + j * 64 + swzH * 8) = phi;
  }
  {
    const unsigned short* vg = vT + (size_t)p * (64 * 256);
#pragma unroll
    for (int it = 0; it < 8; ++it) {
      int idx = it * 256 + tid;
      int d = idx >> 5;
      int c = idx & 31;
      s16x8 val = *(const s16x8*)(vg + d * 256 + c * 8);
      int cs = (c & ~7) | ((c ^ d) & 7);
      *(s16x8*)(Vl + d * 256 + cs * 8) = val;
    }
  }

  s16x8 qa[4][2];
  {
    float cs0[4], sn0[4], cs1[4], sn1[4];
#pragma unroll
    for (int i2 = 0; i2 < 4; ++i2) {
      float f1 = exp2f(-(float)(g * 4 + i2) * F);
      float f2 = exp2f(-(float)(16 + g * 4 + i2) * F);
      sincosf(hh * f1, &sn0[i2], &cs0[i2]);
      sincosf(hh * f2, &sn1[i2], &cs1[i2]);
    }
#pragma unroll
    for (int m = 0; m < 4; ++m) {
      const unsigned short* qg =
          qkv + (size_t)(w * 256 + wv * 64 + m * 16 + r16) * 3072 + h * 64;
      s16x8 lo = *(const s16x8*)(qg + g * 8);
      s16x8 hi = *(const s16x8*)(qg + 32 + g * 8);
      s16x8 plo, phi;
#pragma unroll
      for (int i = 0; i < 8; ++i) {
        int i2 = i >> 1;
        float a = bf2f((unsigned short)lo[i]);
        float b = bf2f((unsigned short)hi[i]);
        plo[i] = (short)f2bf(a * cs0[i2] - b * sn0[i2]);
        phi[i] = (short)f2bf(b * cs1[i2] + a * sn1[i2]);
      }
      qa[m][0] = plo;
      qa[m][1] = phi;
    }
  }

  __syncthreads();

  f32x4 accO[4][4];
  float Mx[4][4], Ls[4][4];
#pragma unroll
  for (int m = 0; m < 4; ++m)
#pragma unroll
    for (int r = 0; r < 4; ++r) {
      Mx[m][r] = -3.0e38f;
      Ls[m][r] = 0.f;
      accO[m][r][0]=0.f; accO[m][r][1]=0.f; accO[m][r][2]=0.f; accO[m][r][3]=0.f;
    }
  unsigned short* Pw = &Pl[wv][0];
  const float zs = 0.125f * 1.44269504f;

  for (int kb = 0; kb < 4; ++kb) {
    f32x4 s[4][4];
#pragma unroll
    for (int m = 0; m < 4; ++m)
#pragma unroll
      for (int jt = 0; jt < 4; ++jt) { s[m][jt][0]=0.f; s[m][jt][1]=0.f; s[m][jt][2]=0.f; s[m][jt][3]=0.f; }

#pragma unroll
    for (int jt = 0; jt < 4; ++jt) {
      int j = kb * 64 + jt * 16 + r16;
      s16x8 bk0 = *(const s16x8*)(Kl + j * 64 + ((g ^ (j & 7)) * 8));
      s16x8 bk1 = *(const s16x8*)(Kl + j * 64 + (((4 + g) ^ (j & 7)) * 8));
#pragma unroll
      for (int m = 0; m < 4; ++m) {
        mfma16(s[m][jt], qa[m][0], bk0);
        mfma16(s[m][jt], qa[m][1], bk1);
      }
    }

#pragma unroll
    for (int m = 0; m < 4; ++m) {
#pragma unroll
      for (int r = 0; r < 4; ++r) {
        float mx = fmaxf(fmaxf(s[m][0][r], s[m][1][r]), fmaxf(s[m][2][r], s[m][3][r]));
        mx = fmaxf(mx, __shfl_xor(mx, 1, 16));
        mx = fmaxf(mx, __shfl_xor(mx, 2, 16));
        mx = fmaxf(mx, __shfl_xor(mx, 4, 16));
        mx = fmaxf(mx, __shfl_xor(mx, 8, 16));
        float Mn = fmaxf(Mx[m][r], mx * zs);
        float fsc = exp2f(Mx[m][r] - Mn);
        Mx[m][r] = Mn;
        float ps = 0.f;
#pragma unroll
        for (int jt = 0; jt < 4; ++jt) {
          float pv = exp2f(s[m][jt][r] * zs - Mn);
          s[m][jt][r] = pv;
          ps += pv;
        }
        ps += __shfl_xor(ps, 1, 16);
        ps += __shfl_xor(ps, 2, 16);
        ps += __shfl_xor(ps, 4, 16);
        ps += __shfl_xor(ps, 8, 16);
        Ls[m][r] = Ls[m][r] * fsc + ps;
#pragma unroll
        for (int dt = 0; dt < 4; ++dt) accO[m][dt][r] *= fsc;
      }
    }

#pragma unroll
    for (int m = 0; m < 4; ++m)
#pragma unroll
      for (int jt = 0; jt < 4; ++jt)
#pragma unroll
        for (int r = 0; r < 4; ++r) {
          int q = m * 16 + g * 4 + r;
          int jj = jt * 16 + r16;
          Pw[q * 88 + jj] = f2bf(s[m][jt][r]);
        }
    asm volatile("s_waitcnt lgkmcnt(0)" ::: "memory");
    __builtin_amdgcn_sched_barrier(0);

#pragma unroll
    for (int c = 0; c < 2; ++c) {
      s16x8 pa[4];
#pragma unroll
      for (int m = 0; m < 4; ++m)
        pa[m] = *(const s16x8*)(Pw + (m * 16 + r16) * 88 + c * 32 + g * 8);
#pragma unroll
      for (int dt = 0; dt < 4; ++dt) {
        int d = dt * 16 + r16;
        int cch = kb * 8 + c * 4 + g;
        int csz = (cch & ~7) | ((cch ^ d) & 7);
        s16x8 vb = *(const s16x8*)(Vl + d * 256 + csz * 8);
#pragma unroll
        for (int m = 0; m < 4; ++m) mfma16(accO[m][dt], pa[m], vb);
      }
    }
    asm volatile("s_waitcnt lgkmcnt(0)" ::: "memory");
    __builtin_amdgcn_sched_barrier(0);
  }

#pragma unroll
  for (int m = 0; m < 4; ++m)
#pragma unroll
    for (int dt = 0; dt < 4; ++dt)
#pragma unroll
      for (int r = 0; r < 4; ++r) {
        int rg = w * 256 + wv * 64 + m * 16 + g * 4 + r;
        int cg = h * 64 + dt * 16 + r16;
        float val = accO[m][dt][r] / Ls[m][r];
        attnout[(size_t)rg * 1024 + cg] = f2bf(val);
      }
}

// ---------------------------------------------------------------------------
// In-place h = silu(w1)*w2 into cols 0..2815 of each 5632-wide row.
// ---------------------------------------------------------------------------
__global__ void silu_mul_kernel(unsigned short* __restrict__ w12o)
{
  int row = blockIdx.x;
  unsigned short* r1 = w12o + (size_t)row * 5632;
  const unsigned short* r2 = r1 + 2816;
  for (int cidx = threadIdx.x; cidx < 352; cidx += 256) {
    s16x8 a = *(const s16x8*)(r1 + cidx * 8);
    s16x8 b = *(const s16x8*)(r2 + cidx * 8);
    s16x8 o;
#pragma unroll
    for (int i = 0; i < 8; ++i) {
      float av = bf2f((unsigned short)a[i]);
      float bv = bf2f((unsigned short)b[i]);
      float sv = av / (1.f + __expf(-av));
      o[i] = (short)f2bf(sv * bv);
    }
    *(s16x8*)(r1 + cidx * 8) = o;
  }
}

// ---------------------------------------------------------------------------
extern "C" void kernel_launch(void* const* d_in, const int* in_sizes, int n_in,
                              void* d_out, int out_size, void* d_ws, size_t ws_size,
                              hipStream_t stream)
{
  const float* x    = (const float*)d_in[0];
  const float* c    = (const float*)d_in[1];
  const float* n1s  = (const float*)d_in[2];
  const float* n2s  = (const float*)d_in[3];
  const float* adaW = (const float*)d_in[4];
  const float* adaB = (const float*)d_in[5];
  const float* qkvW = (const float*)d_in[6];
  const float* qkvB = (const float*)d_in[7];
  const float* outW = (const float*)d_in[8];
  const float* outB = (const float*)d_in[9];
  const float* w12W = (const float*)d_in[10];
  const float* w12B = (const float*)d_in[11];
  const float* w3W  = (const float*)d_in[12];
  const float* w3B  = (const float*)d_in[13];

  char* ws = (char*)d_ws;
  constexpr size_t OFF_ADA  = 0;
  constexpr size_t OFF_QKVT = 98304;
  constexpr size_t OFF_OUTT = OFF_QKVT + 6291456;
  constexpr size_t OFF_W12T = OFF_OUTT + 2097152;
  constexpr size_t OFF_W3T  = OFF_W12T + 11534336;
  constexpr size_t OFF_BPAD = OFF_W3T + 5767168;
  constexpr size_t OFF_XM   = OFF_BPAD + 22528;
  constexpr size_t OFF_BIG  = OFF_XM + 33554432;
  constexpr size_t OFF_QKVC = OFF_BIG;
  constexpr size_t OFF_VTC  = OFF_BIG + 50331648;
  constexpr size_t OFF_ATTC = OFF_BIG + 67108864;
  constexpr size_t OFF_W12O = OFF_BIG;

  float* ada            = (float*)(ws + OFF_ADA);
  unsigned short* qkvT  = (unsigned short*)(ws + OFF_QKVT);
  unsigned short* outT  = (unsigned short*)(ws + OFF_OUTT);
  unsigned short* w12T  = (unsigned short*)(ws + OFF_W12T);
  unsigned short* w3T   = (unsigned short*)(ws + OFF_W3T);
  float* biasPad        = (float*)(ws + OFF_BPAD);
  unsigned short* xm    = (unsigned short*)(ws + OFF_XM);
  unsigned short* qkvbC = (unsigned short*)(ws + OFF_QKVC);
  unsigned short* vTbC  = (unsigned short*)(ws + OFF_VTC);
  unsigned short* attnC = (unsigned short*)(ws + OFF_ATTC);
  unsigned short* w12oC = (unsigned short*)(ws + OFF_W12O);
  float* x2             = (float*)d_out;

  hipMemsetAsync(w12T, 0, 11534336, stream);
  hipMemsetAsync(w3T, 0, 5767168, stream);
  transpose_w<<<dim3(96, 32), 256, 0, stream>>>(qkvW, 3072, 1024, 0, 3072, qkvT, 1024, 0);
  transpose_w<<<dim3(32, 32), 256, 0, stream>>>(outW, 1024, 1024, 0, 1024, outT, 1024, 0);
  transpose_w<<<dim3(86, 32), 256, 0, stream>>>(w12W, 5460, 1024, 0, 2730, w12T, 1024, 0);
  transpose_w<<<dim3(86, 32), 256, 0, stream>>>(w12W, 5460, 1024, 2730, 2730, w12T, 1024, 2816);
  transpose_w<<<dim3(32, 86), 256, 0, stream>>>(w3W, 1024, 2730, 0, 1024, w3T, 2816, 0);
  biaspad_kernel<<<22, 256, 0, stream>>>(w12B, biasPad);
  ada_kernel<<<dim3(24, 4), 256, 0, stream>>>(c, adaW, adaB, ada);

  // --- attention branch (2 chunks of 8192 rows = 32 windows) ---
  rmsmod_kernel<<<16384, 256, 0, stream>>>(x, n1s, ada, 0, 1024, xm);
  for (int ch = 0; ch < 2; ++ch) {
    const size_t ro = (size_t)ch * 8192;
    gemm256<<<dim3(12, 32), 512, 0, stream>>>(
        xm + ro * 1024, 1024, qkvT, 1024, 3072, 1024, qkvB, qkvbC);
    vtrans_kernel<<<512, 256, 0, stream>>>(qkvbC, vTbC);
    attn_kernel<<<512, 256, 0, stream>>>(qkvbC, vTbC, attnC);
    gemm128<1><<<dim3(8, 64), 256, 0, stream>>>(
        attnC, 1024, outT, 1024, 1024, outB, x2 + ro * 1024, x + ro * 1024,
        ada, 2048, (int)ro);
  }

  // --- MLP branch (2 chunks of 8192 rows) ---
  rmsmod_kernel<<<16384, 256, 0, stream>>>(x2, n2s, ada, 3072, 4096, xm);
  for (int ch = 0; ch < 2; ++ch) {
    const size_t ro = (size_t)ch * 8192;
    gemm256<<<dim3(22, 32), 512, 0, stream>>>(
        xm + ro * 1024, 1024, w12T, 1024, 5632, 1024, biasPad, w12oC);
    silu_mul_kernel<<<8192, 256, 0, stream>>>(w12oC);
    gemm128<3><<<dim3(8, 64), 256, 0, stream>>>(
        w12oC, 5632, w3T, 1024, 2816, w3B, x2 + ro * 1024, x2 + ro * 1024,
        ada, 5120, (int)ro);
  }
}

// Round 4
// 864.808 us; speedup vs baseline: 1.0703x; 1.0417x over previous
//
#include <hip/hip_runtime.h>
#include <hip/hip_bf16.h>
#include <cstdint>
#include <cstddef>

#define DEV __device__ __forceinline__

typedef float f32x4 __attribute__((ext_vector_type(4)));
typedef short s16x8 __attribute__((ext_vector_type(8)));
typedef short s16x4 __attribute__((ext_vector_type(4)));
typedef __bf16 bf16x8 __attribute__((ext_vector_type(8)));

DEV unsigned short f2bf(float f) {
  union { float f; unsigned u; } v; v.f = f;
  return (unsigned short)((v.u + 0x7FFFu + ((v.u >> 16) & 1u)) >> 16);
}
DEV float bf2f(unsigned short s) {
  union { unsigned u; float f; } v; v.u = ((unsigned)s) << 16;
  return v.f;
}

DEV void mfma16(f32x4& d, const s16x8& a, const s16x8& b) {
  d = __builtin_amdgcn_mfma_f32_16x16x32_bf16(
      __builtin_bit_cast(bf16x8, a), __builtin_bit_cast(bf16x8, b), d, 0, 0, 0);
}

typedef const unsigned int gu32 __attribute__((address_space(1)));
typedef unsigned int lu32 __attribute__((address_space(3)));
DEV void gl_lds16(const void* g, void* l) {
  __builtin_amdgcn_global_load_lds((gu32*)g, (lu32*)l, 16, 0, 0);
}

// ---------------------------------------------------------------------------
// Weight transpose fp32 (K x N, submatrix) -> bf16 (N x Kp) at dst rowOff.
// ilv=1: interleave-16 row mapping dstRow = (n/16)*32 + (n%16) + rowOff.
// ---------------------------------------------------------------------------
__global__ void transpose_w(const float* __restrict__ src, int srcLd, int K,
                            int colOff, int nCols,
                            unsigned short* __restrict__ dst, int dstLd, int rowOff,
                            int ilv)
{
  __shared__ float tile[32][33];
  int tx = threadIdx.x & 31, ty = threadIdx.x >> 5;
  int k0 = blockIdx.y * 32, n0 = blockIdx.x * 32;
#pragma unroll
  for (int r = 0; r < 4; ++r) {
    int kk = k0 + ty + r * 8;
    int nn = n0 + tx;
    if (kk < K && nn < nCols) tile[ty + r * 8][tx] = src[(size_t)kk * srcLd + colOff + nn];
  }
  __syncthreads();
#pragma unroll
  for (int r = 0; r < 4; ++r) {
    int nn = n0 + ty + r * 8;
    int kk = k0 + tx;
    if (nn < nCols && kk < K) {
      int row = ilv ? (((nn >> 4) << 5) + (nn & 15) + rowOff) : (rowOff + nn);
      dst[(size_t)row * dstLd + kk] = f2bf(tile[tx][ty + r * 8]);
    }
  }
}

// ---------------------------------------------------------------------------
// biasPad for interleaved w12: col n -> block bb=n/16 (even: w1, odd: w2)
// ---------------------------------------------------------------------------
__global__ void biaspad_kernel(const float* __restrict__ b, float* __restrict__ out)
{
  int n = blockIdx.x * 256 + threadIdx.x;
  if (n >= 5632) return;
  int bb = n >> 4, i = n & 15;
  int src = ((bb >> 1) << 4) + i;
  float v = 0.f;
  if (src < 2730) v = (bb & 1) ? b[2730 + src] : b[src];
  out[n] = v;
}

// ---------------------------------------------------------------------------
// ada = silu(c) @ adaLN_w + adaLN_b    (B=4, K=1024, N=6144)
// ---------------------------------------------------------------------------
__global__ void ada_kernel(const float* __restrict__ c, const float* __restrict__ w,
                           const float* __restrict__ b, float* __restrict__ ada)
{
  __shared__ float cs[1024];
  int bb = blockIdx.y;
  int j = blockIdx.x * 256 + threadIdx.x;
  for (int i = threadIdx.x; i < 1024; i += 256) {
    float v = c[bb * 1024 + i];
    cs[i] = v / (1.f + __expf(-v));
  }
  __syncthreads();
  float acc = b[j];
  for (int k = 0; k < 1024; ++k) acc = fmaf(cs[k], w[(size_t)k * 6144 + j], acc);
  ada[bb * 6144 + j] = acc;
}

// ---------------------------------------------------------------------------
// xm = ((x * rsqrt(mean(x^2)+eps)) * nscale) * (1+sc) + sh   -> bf16
// ---------------------------------------------------------------------------
__global__ void rmsmod_kernel(const float* __restrict__ x, const float* __restrict__ nsc,
                              const float* __restrict__ ada, int shOff, int scOff,
                              unsigned short* __restrict__ out)
{
  int row = blockIdx.x;
  int t = threadIdx.x;
  const f32x4* xr = (const f32x4*)(x + (size_t)row * 1024);
  f32x4 v = xr[t];
  float ss = v[0]*v[0] + v[1]*v[1] + v[2]*v[2] + v[3]*v[3];
#pragma unroll
  for (int off = 32; off >= 1; off >>= 1) ss += __shfl_xor(ss, off, 64);
  __shared__ float red[4];
  int lane = t & 63, wv = t >> 6;
  if (lane == 0) red[wv] = ss;
  __syncthreads();
  float tot = red[0] + red[1] + red[2] + red[3];
  float rms = rsqrtf(tot * (1.f / 1024.f) + 1e-6f);
  int bb = row >> 12;
  const float* ab = ada + bb * 6144;
  s16x4 o;
#pragma unroll
  for (int i = 0; i < 4; ++i) {
    int col = t * 4 + i;
    float xn = v[i] * rms * nsc[col];
    float val = xn * (1.f + ab[scOff + col]) + ab[shOff + col];
    o[i] = (short)f2bf(val);
  }
  *(s16x4*)(out + (size_t)row * 1024 + t * 4) = o;
}

// ---------------------------------------------------------------------------
// gemm256: C = A(bf16 MxK, stride lda) * BT(bf16 NxK, stride ldb)^T + bias.
// 256x256 tile, BK=64, 8 waves (2Mx4N), 4 quadrant-phases per K-tile,
// deep staging: tile t+2's B-halves staged at ph2 of tile t, A-halves at ph3,
// single counted vmcnt(8) per K-tile (1 full tile allowed in flight).
// EPI=0: bf16 store + bias (Nout = N)
// EPI=1: interleave-16 silu-pair epilogue -> h = silu(v1)*v2, Nout = N/2
// LDS: 2 x (A 32KB + B 32KB) = 128 KiB. Requires M%256==0, N%256==0,
// K%64==0, K/64>=2, grid multiple of 8.
// ---------------------------------------------------------------------------
template<int EPI>
__global__ __launch_bounds__(512, 2) void gemm256(
    const unsigned short* __restrict__ A, int lda,
    const unsigned short* __restrict__ BT, int ldb,
    int N, int K,
    const float* __restrict__ bias,
    unsigned short* __restrict__ Cout, int Nout)
{
  __shared__ __align__(16) char lds[131072];

  const int tid = threadIdx.x;
  const int lane = tid & 63;
  const int wv = tid >> 6;
  const int wr = wv >> 2;        // 0..1  (M half)
  const int wn = wv & 3;         // 0..3  (N quarter)
  const int g = lane >> 4, r16 = lane & 15;

  // XCD-aware bijective block swizzle (grid % 8 == 0 guaranteed by caller)
  const int nwg = gridDim.x * gridDim.y;
  const int bid = blockIdx.x + gridDim.x * blockIdx.y;
  const int qq = nwg >> 3;
  const int swz = (bid & 7) * qq + (bid >> 3);
  const int m0 = (swz / gridDim.x) * 256;
  const int n0 = (swz % gridDim.x) * 256;

  const int nkt = K >> 6;

  // stage one half-tile (t, s): s 0=B rows0-127, 1=B rows128-255, 2=A rows0-127, 3=A rows128-255
  auto stage_half = [&](int t, int s) {
    if (t >= nkt) return;
    const int bs = t & 1;
#pragma unroll
    for (int it = 0; it < 2; ++it) {
      const int cidx = it * 512 + tid;
      const int rl = cidx >> 3, cc = cidx & 7;
      if (s >= 2) {
        const int row = (s - 2) * 128 + rl;
        const unsigned short* src =
            A + (size_t)(m0 + row) * lda + t * 64 + ((cc ^ (row & 7)) << 3);
        gl_lds16(src, lds + bs * 32768 + (s - 2) * 16384 + cidx * 16);
      } else {
        const int row = s * 128 + rl;
        const unsigned short* src =
            BT + (size_t)(n0 + row) * ldb + t * 64 + ((cc ^ (row & 7)) << 3);
        gl_lds16(src, lds + 65536 + bs * 32768 + s * 16384 + cidx * 16);
      }
    }
  };

  f32x4 acc[8][4];
#pragma unroll
  for (int m = 0; m < 8; ++m)
#pragma unroll
    for (int n = 0; n < 4; ++n) { acc[m][n][0]=0.f; acc[m][n][1]=0.f; acc[m][n][2]=0.f; acc[m][n][3]=0.f; }

  int swzk[2];
#pragma unroll
  for (int ks = 0; ks < 2; ++ks) swzk[ks] = (((ks << 2) + g) ^ (r16 & 7)) << 4;
  int arow0[4], arow1[4], brow0[2], brow1[2];
#pragma unroll
  for (int m = 0; m < 4; ++m) {
    arow0[m] = (wr * 128 + m * 16 + r16) * 128;
    arow1[m] = (wr * 128 + 64 + m * 16 + r16) * 128;
  }
#pragma unroll
  for (int n = 0; n < 2; ++n) {
    brow0[n] = 65536 + (wn * 64 + n * 16 + r16) * 128;
    brow1[n] = 65536 + (wn * 64 + 32 + n * 16 + r16) * 128;
  }

  // prologue: stage tiles 0 and 1 fully; require tile 0 landed (vmcnt(8) = 1 tile out)
  stage_half(0, 0); stage_half(0, 1); stage_half(0, 2); stage_half(0, 3);
  stage_half(1, 0); stage_half(1, 1); stage_half(1, 2); stage_half(1, 3);
  asm volatile("s_waitcnt vmcnt(8)" ::: "memory");
  __builtin_amdgcn_s_barrier();

  s16x8 af[4][2], b0[2][2], b1[2][2];

  for (int kt = 0; kt < nkt; ++kt) {
    const int boff = (kt & 1) * 32768;
    // ---------------- phase 0: quadrant (mh0, nh0) ----------------
#pragma unroll
    for (int m = 0; m < 4; ++m)
#pragma unroll
      for (int ks = 0; ks < 2; ++ks)
        af[m][ks] = *(const s16x8*)(lds + boff + arow0[m] + swzk[ks]);
#pragma unroll
    for (int n = 0; n < 2; ++n)
#pragma unroll
      for (int ks = 0; ks < 2; ++ks)
        b0[n][ks] = *(const s16x8*)(lds + boff + brow0[n] + swzk[ks]);
    __builtin_amdgcn_sched_barrier(0);
    __builtin_amdgcn_s_barrier();
    asm volatile("s_waitcnt lgkmcnt(0)" ::: "memory");
    __builtin_amdgcn_sched_barrier(0);
    __builtin_amdgcn_s_setprio(1);
#pragma unroll
    for (int m = 0; m < 4; ++m)
#pragma unroll
      for (int n = 0; n < 2; ++n)
#pragma unroll
        for (int ks = 0; ks < 2; ++ks)
          mfma16(acc[m][n], af[m][ks], b0[n][ks]);
    __builtin_amdgcn_s_setprio(0);
    __builtin_amdgcn_sched_barrier(0);
    __builtin_amdgcn_s_barrier();
    // ---------------- phase 1: quadrant (mh0, nh1) ----------------
#pragma unroll
    for (int n = 0; n < 2; ++n)
#pragma unroll
      for (int ks = 0; ks < 2; ++ks)
        b1[n][ks] = *(const s16x8*)(lds + boff + brow1[n] + swzk[ks]);
    __builtin_amdgcn_sched_barrier(0);
    __builtin_amdgcn_s_barrier();
    asm volatile("s_waitcnt lgkmcnt(0)" ::: "memory");
    __builtin_amdgcn_sched_barrier(0);
    __builtin_amdgcn_s_setprio(1);
#pragma unroll
    for (int m = 0; m < 4; ++m)
#pragma unroll
      for (int n = 0; n < 2; ++n)
#pragma unroll
        for (int ks = 0; ks < 2; ++ks)
          mfma16(acc[m][2 + n], af[m][ks], b1[n][ks]);
    __builtin_amdgcn_s_setprio(0);
    __builtin_amdgcn_sched_barrier(0);
    __builtin_amdgcn_s_barrier();
    // ---------------- phase 2: quadrant (mh1, nh1); stage B(kt+2) ----------------
#pragma unroll
    for (int m = 0; m < 4; ++m)
#pragma unroll
      for (int ks = 0; ks < 2; ++ks)
        af[m][ks] = *(const s16x8*)(lds + boff + arow1[m] + swzk[ks]);
    stage_half(kt + 2, 0);
    stage_half(kt + 2, 1);
    __builtin_amdgcn_sched_barrier(0);
    __builtin_amdgcn_s_barrier();
    asm volatile("s_waitcnt lgkmcnt(0)" ::: "memory");
    __builtin_amdgcn_sched_barrier(0);
    __builtin_amdgcn_s_setprio(1);
#pragma unroll
    for (int m = 0; m < 4; ++m)
#pragma unroll
      for (int n = 0; n < 2; ++n)
#pragma unroll
        for (int ks = 0; ks < 2; ++ks)
          mfma16(acc[4 + m][2 + n], af[m][ks], b1[n][ks]);
    __builtin_amdgcn_s_setprio(0);
    __builtin_amdgcn_sched_barrier(0);
    __builtin_amdgcn_s_barrier();
    // ---------------- phase 3: quadrant (mh1, nh0); stage A(kt+2) ----------------
    stage_half(kt + 2, 2);
    stage_half(kt + 2, 3);
    __builtin_amdgcn_sched_barrier(0);
    __builtin_amdgcn_s_barrier();
    __builtin_amdgcn_s_setprio(1);
#pragma unroll
    for (int m = 0; m < 4; ++m)
#pragma unroll
      for (int n = 0; n < 2; ++n)
#pragma unroll
        for (int ks = 0; ks < 2; ++ks)
          mfma16(acc[4 + m][n], af[m][ks], b0[n][ks]);
    __builtin_amdgcn_s_setprio(0);
    __builtin_amdgcn_sched_barrier(0);
    asm volatile("s_waitcnt vmcnt(8)" ::: "memory");
    __builtin_amdgcn_s_barrier();
  }

  if (EPI == 0) {
#pragma unroll
    for (int fm = 0; fm < 8; ++fm)
#pragma unroll
      for (int fn = 0; fn < 4; ++fn)
#pragma unroll
        for (int r = 0; r < 4; ++r) {
          int rg = m0 + wr * 128 + fm * 16 + g * 4 + r;
          int cg = n0 + wn * 64 + fn * 16 + r16;
          Cout[(size_t)rg * Nout + cg] = f2bf(acc[fm][fn][r] + bias[cg]);
        }
  } else {
    // silu-pair epilogue: fragments (2p, 2p+1) hold matched w1/w2 columns
#pragma unroll
    for (int fm = 0; fm < 8; ++fm)
#pragma unroll
      for (int p = 0; p < 2; ++p)
#pragma unroll
        for (int r = 0; r < 4; ++r) {
          int rg = m0 + wr * 128 + fm * 16 + g * 4 + r;
          int cg = n0 + wn * 64 + (2 * p) * 16 + r16;
          float v1 = acc[fm][2 * p][r] + bias[cg];
          float v2 = acc[fm][2 * p + 1][r] + bias[cg + 16];
          float h = v1 / (1.f + __expf(-v1)) * v2;
          int hcol = (n0 >> 1) + wn * 32 + p * 16 + r16;
          Cout[(size_t)rg * Nout + hcol] = f2bf(h);
        }
  }
}

// ---------------------------------------------------------------------------
// GEMM 128x128 (2-barrier structure) for the N=1024 GEMMs.
// MODE 1/3: f32 store res + gate*(v+b)
// ---------------------------------------------------------------------------
template<int MODE>
__global__ void gemm128(const unsigned short* __restrict__ A, int lda,
                        const unsigned short* __restrict__ BT,
                        int N, int K,
                        const float* __restrict__ bias,
                        void* __restrict__ Cout,
                        const float* __restrict__ res,
                        const float* __restrict__ ada, int gateOff, int mOff)
{
  __shared__ __align__(16) unsigned short As[128 * 32];
  __shared__ __align__(16) unsigned short Bs[128 * 32];

  const int tid = threadIdx.x;
  const int lane = tid & 63;
  const int wv = tid >> 6;
  const int wr = wv >> 1, wc = wv & 1;
  const int g = lane >> 4, r16 = lane & 15;
  const int m0 = blockIdx.y * 128, n0 = blockIdx.x * 128;

  const int c0 = tid, c1 = 256 + tid;
  const int ra0 = c0 >> 2, ra1 = c1 >> 2;
  const int k0 = ((c0 & 3) ^ ((ra0 >> 1) & 3)) * 8;
  const int k1 = ((c1 & 3) ^ ((ra1 >> 1) & 3)) * 8;
  const unsigned short* ga0 = A + (size_t)(m0 + ra0) * lda + k0;
  const unsigned short* ga1 = A + (size_t)(m0 + ra1) * lda + k1;
  const unsigned short* gb0 = BT + (size_t)(n0 + ra0) * K + k0;
  const unsigned short* gb1 = BT + (size_t)(n0 + ra1) * K + k1;
  unsigned short* la0 = As + c0 * 8;
  unsigned short* la1 = As + c1 * 8;
  unsigned short* lb0 = Bs + c0 * 8;
  unsigned short* lb1 = Bs + c1 * 8;

  f32x4 acc[4][4];
#pragma unroll
  for (int m = 0; m < 4; ++m)
#pragma unroll
    for (int n = 0; n < 4; ++n) { acc[m][n][0]=0.f; acc[m][n][1]=0.f; acc[m][n][2]=0.f; acc[m][n][3]=0.f; }

  int aoff[4], boff[4];
#pragma unroll
  for (int m = 0; m < 4; ++m) {
    int rl = wr * 64 + m * 16 + r16;
    aoff[m] = rl * 32 + (g ^ ((rl >> 1) & 3)) * 8;
    int rb = wc * 64 + m * 16 + r16;
    boff[m] = rb * 32 + (g ^ ((rb >> 1) & 3)) * 8;
  }

  const int nk = K >> 5;
  for (int kt = 0; kt < nk; ++kt) {
    __syncthreads();
    const int ko = kt * 32;
    gl_lds16(ga0 + ko, la0);
    gl_lds16(ga1 + ko, la1);
    gl_lds16(gb0 + ko, lb0);
    gl_lds16(gb1 + ko, lb1);
    __syncthreads();
    s16x8 af[4], bf[4];
#pragma unroll
    for (int m = 0; m < 4; ++m) af[m] = *(const s16x8*)(As + aoff[m]);
#pragma unroll
    for (int n = 0; n < 4; ++n) bf[n] = *(const s16x8*)(Bs + boff[n]);
#pragma unroll
    for (int m = 0; m < 4; ++m)
#pragma unroll
      for (int n = 0; n < 4; ++n) mfma16(acc[m][n], af[m], bf[n]);
  }

#pragma unroll
  for (int m = 0; m < 4; ++m) {
#pragma unroll
    for (int n = 0; n < 4; ++n) {
#pragma unroll
      for (int r = 0; r < 4; ++r) {
        int rg = m0 + wr * 64 + m * 16 + g * 4 + r;
        int cg = n0 + wc * 64 + n * 16 + r16;
        float v = acc[m][n][r] + bias[cg];
        size_t idx = (size_t)rg * N + cg;
        if (MODE == 0 || MODE == 2) {
          ((unsigned short*)Cout)[idx] = f2bf(v);
        } else {
          int bb = (mOff + rg) >> 12;
          float gate = ada[bb * 6144 + gateOff + cg];
          ((float*)Cout)[idx] = res[idx] + gate * v;
        }
      }
    }
  }
}

// ---------------------------------------------------------------------------
// V transpose: qkv v-part (per window/head 256j x 64d) -> vT[pair][64d][256j]
// ---------------------------------------------------------------------------
__global__ void vtrans_kernel(const unsigned short* __restrict__ qkv,
                              unsigned short* __restrict__ vT)
{
  __shared__ unsigned short tl[64][72];
  int pidx = blockIdx.x;
  int w = pidx >> 4, h = pidx & 15;
  int t = threadIdx.x;
  for (int jb = 0; jb < 4; ++jb) {
    int jl = t >> 2, dc = t & 3;
    const unsigned short* srcp =
        qkv + (size_t)(w * 256 + jb * 64 + jl) * 3072 + 2048 + h * 64 + dc * 16;
    s16x8 v0 = *(const s16x8*)(srcp);
    s16x8 v1 = *(const s16x8*)(srcp + 8);
    if (jb) __syncthreads();
    *(s16x8*)(&tl[jl][dc * 16]) = v0;
    *(s16x8*)(&tl[jl][dc * 16 + 8]) = v1;
    __syncthreads();
    int dl = t >> 2, jc = t & 3;
    s16x8 o0, o1;
#pragma unroll
    for (int i = 0; i < 8; ++i) {
      o0[i] = (short)tl[jc * 16 + i][dl];
      o1[i] = (short)tl[jc * 16 + 8 + i][dl];
    }
    unsigned short* dstp = vT + (size_t)pidx * (64 * 256) + (size_t)dl * 256 + jb * 64 + jc * 16;
    *(s16x8*)(dstp) = o0;
    *(s16x8*)(dstp + 8) = o1;
  }
}

// ---------------------------------------------------------------------------
// Fused windowed attention, one block per (window, head). 4 waves x 64 q-rows.
// ---------------------------------------------------------------------------
__global__ __launch_bounds__(256, 1) void attn_kernel(
    const unsigned short* __restrict__ qkv,
    const unsigned short* __restrict__ vT,
    unsigned short* __restrict__ attnout)
{
  __shared__ __align__(16) unsigned short Kl[256 * 64];
  __shared__ __align__(16) unsigned short Vl[64 * 256];
  __shared__ __align__(16) unsigned short Pl[4][64 * 88];

  const int tid = threadIdx.x;
  const int lane = tid & 63;
  const int wv = tid >> 6;
  const int g = lane >> 4, r16 = lane & 15;
  const int p = blockIdx.x;
  const int w = p >> 4, h = p & 15;
  const float hh = (float)h;
  const float F = 0.4152410118609203f; // log2(10000)/32

#pragma unroll
  for (int it = 0; it < 4; ++it) {
    int idx = it * 256 + tid;
    int j = idx >> 2;
    int c = idx & 3;
    const unsigned short* kg = qkv + (size_t)(w * 256 + j) * 3072 + 1024 + h * 64;
    s16x8 lo = *(const s16x8*)(kg + c * 8);
    s16x8 hi = *(const s16x8*)(kg + 32 + c * 8);
    s16x8 plo, phi;
#pragma unroll
    for (int i2 = 0; i2 < 4; ++i2) {
      float f1 = exp2f(-(float)(c * 4 + i2) * F);
      float f2 = exp2f(-(float)(16 + c * 4 + i2) * F);
      float s1, c1s, s2, c2s;
      sincosf(hh * f1, &s1, &c1s);
      sincosf(hh * f2, &s2, &c2s);
#pragma unroll
      for (int u = 0; u < 2; ++u) {
        int i = i2 * 2 + u;
        float a = bf2f((unsigned short)lo[i]);
        float b = bf2f((unsigned short)hi[i]);
        plo[i] = (short)f2bf(a * c1s - b * s1);
        phi[i] = (short)f2bf(b * c2s + a * s2);
      }
    }
    int swzL = c ^ (j & 7);
    int swzH = (c + 4) ^ (j & 7);
    *(s16x8*)(Kl + j * 64 + swzL * 8) = plo;
    *(s16x8*)(Kl + j * 64 + swzH * 8) = phi;
  }
  {
    const unsigned short* vg = vT + (size_t)p * (64 * 256);
#pragma unroll
    for (int it = 0; it < 8; ++it) {
      int idx = it * 256 + tid;
      int d = idx >> 5;
      int c = idx & 31;
      s16x8 val = *(const s16x8*)(vg + d * 256 + c * 8);
      int cs = (c & ~7) | ((c ^ d) & 7);
      *(s16x8*)(Vl + d * 256 + cs * 8) = val;
    }
  }

  s16x8 qa[4][2];
  {
    float cs0[4], sn0[4], cs1[4], sn1[4];
#pragma unroll
    for (int i2 = 0; i2 < 4; ++i2) {
      float f1 = exp2f(-(float)(g * 4 + i2) * F);
      float f2 = exp2f(-(float)(16 + g * 4 + i2) * F);
      sincosf(hh * f1, &sn0[i2], &cs0[i2]);
      sincosf(hh * f2, &sn1[i2], &cs1[i2]);
    }
#pragma unroll
    for (int m = 0; m < 4; ++m) {
      const unsigned short* qg =
          qkv + (size_t)(w * 256 + wv * 64 + m * 16 + r16) * 3072 + h * 64;
      s16x8 lo = *(const s16x8*)(qg + g * 8);
      s16x8 hi = *(const s16x8*)(qg + 32 + g * 8);
      s16x8 plo, phi;
#pragma unroll
      for (int i = 0; i < 8; ++i) {
        int i2 = i >> 1;
        float a = bf2f((unsigned short)lo[i]);
        float b = bf2f((unsigned short)hi[i]);
        plo[i] = (short)f2bf(a * cs0[i2] - b * sn0[i2]);
        phi[i] = (short)f2bf(b * cs1[i2] + a * sn1[i2]);
      }
      qa[m][0] = plo;
      qa[m][1] = phi;
    }
  }

  __syncthreads();

  f32x4 accO[4][4];
  float Mx[4][4], Ls[4][4];
#pragma unroll
  for (int m = 0; m < 4; ++m)
#pragma unroll
    for (int r = 0; r < 4; ++r) {
      Mx[m][r] = -3.0e38f;
      Ls[m][r] = 0.f;
      accO[m][r][0]=0.f; accO[m][r][1]=0.f; accO[m][r][2]=0.f; accO[m][r][3]=0.f;
    }
  unsigned short* Pw = &Pl[wv][0];
  const float zs = 0.125f * 1.44269504f;

  for (int kb = 0; kb < 4; ++kb) {
    f32x4 s[4][4];
#pragma unroll
    for (int m = 0; m < 4; ++m)
#pragma unroll
      for (int jt = 0; jt < 4; ++jt) { s[m][jt][0]=0.f; s[m][jt][1]=0.f; s[m][jt][2]=0.f; s[m][jt][3]=0.f; }

#pragma unroll
    for (int jt = 0; jt < 4; ++jt) {
      int j = kb * 64 + jt * 16 + r16;
      s16x8 bk0 = *(const s16x8*)(Kl + j * 64 + ((g ^ (j & 7)) * 8));
      s16x8 bk1 = *(const s16x8*)(Kl + j * 64 + (((4 + g) ^ (j & 7)) * 8));
#pragma unroll
      for (int m = 0; m < 4; ++m) {
        mfma16(s[m][jt], qa[m][0], bk0);
        mfma16(s[m][jt], qa[m][1], bk1);
      }
    }

#pragma unroll
    for (int m = 0; m < 4; ++m) {
#pragma unroll
      for (int r = 0; r < 4; ++r) {
        float mx = fmaxf(fmaxf(s[m][0][r], s[m][1][r]), fmaxf(s[m][2][r], s[m][3][r]));
        mx = fmaxf(mx, __shfl_xor(mx, 1, 16));
        mx = fmaxf(mx, __shfl_xor(mx, 2, 16));
        mx = fmaxf(mx, __shfl_xor(mx, 4, 16));
        mx = fmaxf(mx, __shfl_xor(mx, 8, 16));
        float Mn = fmaxf(Mx[m][r], mx * zs);
        float fsc = exp2f(Mx[m][r] - Mn);
        Mx[m][r] = Mn;
        float ps = 0.f;
#pragma unroll
        for (int jt = 0; jt < 4; ++jt) {
          float pv = exp2f(s[m][jt][r] * zs - Mn);
          s[m][jt][r] = pv;
          ps += pv;
        }
        ps += __shfl_xor(ps, 1, 16);
        ps += __shfl_xor(ps, 2, 16);
        ps += __shfl_xor(ps, 4, 16);
        ps += __shfl_xor(ps, 8, 16);
        Ls[m][r] = Ls[m][r] * fsc + ps;
#pragma unroll
        for (int dt = 0; dt < 4; ++dt) accO[m][dt][r] *= fsc;
      }
    }

#pragma unroll
    for (int m = 0; m < 4; ++m)
#pragma unroll
      for (int jt = 0; jt < 4; ++jt)
#pragma unroll
        for (int r = 0; r < 4; ++r) {
          int q = m * 16 + g * 4 + r;
          int jj = jt * 16 + r16;
          Pw[q * 88 + jj] = f2bf(s[m][jt][r]);
        }
    asm volatile("s_waitcnt lgkmcnt(0)" ::: "memory");
    __builtin_amdgcn_sched_barrier(0);

#pragma unroll
    for (int c = 0; c < 2; ++c) {
      s16x8 pa[4];
#pragma unroll
      for (int m = 0; m < 4; ++m)
        pa[m] = *(const s16x8*)(Pw + (m * 16 + r16) * 88 + c * 32 + g * 8);
#pragma unroll
      for (int dt = 0; dt < 4; ++dt) {
        int d = dt * 16 + r16;
        int cch = kb * 8 + c * 4 + g;
        int csz = (cch & ~7) | ((cch ^ d) & 7);
        s16x8 vb = *(const s16x8*)(Vl + d * 256 + csz * 8);
#pragma unroll
        for (int m = 0; m < 4; ++m) mfma16(accO[m][dt], pa[m], vb);
      }
    }
    asm volatile("s_waitcnt lgkmcnt(0)" ::: "memory");
    __builtin_amdgcn_sched_barrier(0);
  }

#pragma unroll
  for (int m = 0; m < 4; ++m)
#pragma unroll
    for (int dt = 0; dt < 4; ++dt)
#pragma unroll
      for (int r = 0; r < 4; ++r) {
        int rg = w * 256 + wv * 64 + m * 16 + g * 4 + r;
        int cg = h * 64 + dt * 16 + r16;
        float val = accO[m][dt][r] / Ls[m][r];
        attnout[(size_t)rg * 1024 + cg] = f2bf(val);
      }
}

// ---------------------------------------------------------------------------
extern "C" void kernel_launch(void* const* d_in, const int* in_sizes, int n_in,
                              void* d_out, int out_size, void* d_ws, size_t ws_size,
                              hipStream_t stream)
{
  const float* x    = (const float*)d_in[0];
  const float* c    = (const float*)d_in[1];
  const float* n1s  = (const float*)d_in[2];
  const float* n2s  = (const float*)d_in[3];
  const float* adaW = (const float*)d_in[4];
  const float* adaB = (const float*)d_in[5];
  const float* qkvW = (const float*)d_in[6];
  const float* qkvB = (const float*)d_in[7];
  const float* outW = (const float*)d_in[8];
  const float* outB = (const float*)d_in[9];
  const float* w12W = (const float*)d_in[10];
  const float* w12B = (const float*)d_in[11];
  const float* w3W  = (const float*)d_in[12];
  const float* w3B  = (const float*)d_in[13];

  char* ws = (char*)d_ws;
  constexpr size_t OFF_ADA  = 0;
  constexpr size_t OFF_QKVT = 98304;
  constexpr size_t OFF_OUTT = OFF_QKVT + 6291456;
  constexpr size_t OFF_W12T = OFF_OUTT + 2097152;
  constexpr size_t OFF_W3T  = OFF_W12T + 11534336;
  constexpr size_t OFF_BPAD = OFF_W3T + 5767168;
  constexpr size_t OFF_XM   = OFF_BPAD + 22528;
  constexpr size_t OFF_BIG  = OFF_XM + 33554432;
  constexpr size_t OFF_QKVC = OFF_BIG;
  constexpr size_t OFF_VTC  = OFF_BIG + 50331648;
  constexpr size_t OFF_ATTC = OFF_BIG + 67108864;
  constexpr size_t OFF_HBUF = OFF_BIG;            // M x 2816 bf16 per chunk (46 MB)

  float* ada            = (float*)(ws + OFF_ADA);
  unsigned short* qkvT  = (unsigned short*)(ws + OFF_QKVT);
  unsigned short* outT  = (unsigned short*)(ws + OFF_OUTT);
  unsigned short* w12T  = (unsigned short*)(ws + OFF_W12T);
  unsigned short* w3T   = (unsigned short*)(ws + OFF_W3T);
  float* biasPad        = (float*)(ws + OFF_BPAD);
  unsigned short* xm    = (unsigned short*)(ws + OFF_XM);
  unsigned short* qkvbC = (unsigned short*)(ws + OFF_QKVC);
  unsigned short* vTbC  = (unsigned short*)(ws + OFF_VTC);
  unsigned short* attnC = (unsigned short*)(ws + OFF_ATTC);
  unsigned short* hbufC = (unsigned short*)(ws + OFF_HBUF);
  float* x2             = (float*)d_out;

  hipMemsetAsync(w12T, 0, 11534336, stream);
  hipMemsetAsync(w3T, 0, 5767168, stream);
  transpose_w<<<dim3(96, 32), 256, 0, stream>>>(qkvW, 3072, 1024, 0, 3072, qkvT, 1024, 0, 0);
  transpose_w<<<dim3(32, 32), 256, 0, stream>>>(outW, 1024, 1024, 0, 1024, outT, 1024, 0, 0);
  transpose_w<<<dim3(86, 32), 256, 0, stream>>>(w12W, 5460, 1024, 0, 2730, w12T, 1024, 0, 1);
  transpose_w<<<dim3(86, 32), 256, 0, stream>>>(w12W, 5460, 1024, 2730, 2730, w12T, 1024, 16, 1);
  transpose_w<<<dim3(32, 86), 256, 0, stream>>>(w3W, 1024, 2730, 0, 1024, w3T, 2816, 0, 0);
  biaspad_kernel<<<22, 256, 0, stream>>>(w12B, biasPad);
  ada_kernel<<<dim3(24, 4), 256, 0, stream>>>(c, adaW, adaB, ada);

  // --- attention branch (2 chunks of 8192 rows = 32 windows) ---
  rmsmod_kernel<<<16384, 256, 0, stream>>>(x, n1s, ada, 0, 1024, xm);
  for (int ch = 0; ch < 2; ++ch) {
    const size_t ro = (size_t)ch * 8192;
    gemm256<0><<<dim3(12, 32), 512, 0, stream>>>(
        xm + ro * 1024, 1024, qkvT, 1024, 3072, 1024, qkvB, qkvbC, 3072);
    vtrans_kernel<<<512, 256, 0, stream>>>(qkvbC, vTbC);
    attn_kernel<<<512, 256, 0, stream>>>(qkvbC, vTbC, attnC);
    gemm128<1><<<dim3(8, 64), 256, 0, stream>>>(
        attnC, 1024, outT, 1024, 1024, outB, x2 + ro * 1024, x + ro * 1024,
        ada, 2048, (int)ro);
  }

  // --- MLP branch (2 chunks of 8192 rows) ---
  rmsmod_kernel<<<16384, 256, 0, stream>>>(x2, n2s, ada, 3072, 4096, xm);
  for (int ch = 0; ch < 2; ++ch) {
    const size_t ro = (size_t)ch * 8192;
    gemm256<1><<<dim3(22, 32), 512, 0, stream>>>(
        xm + ro * 1024, 1024, w12T, 1024, 5632, 1024, biasPad, hbufC, 2816);
    gemm128<3><<<dim3(8, 64), 256, 0, stream>>>(
        hbufC, 2816, w3T, 1024, 2816, w3B, x2 + ro * 1024, x2 + ro * 1024,
        ada, 5120, (int)ro);
  }
}

// Round 5
// 763.814 us; speedup vs baseline: 1.2119x; 1.1322x over previous
//
#include <hip/hip_runtime.h>
#include <hip/hip_bf16.h>
#include <cstdint>
#include <cstddef>

#define DEV __device__ __forceinline__

typedef float f32x4 __attribute__((ext_vector_type(4)));
typedef short s16x8 __attribute__((ext_vector_type(8)));
typedef short s16x4 __attribute__((ext_vector_type(4)));
typedef __bf16 bf16x8 __attribute__((ext_vector_type(8)));

DEV unsigned short f2bf(float f) {
  union { float f; unsigned u; } v; v.f = f;
  return (unsigned short)((v.u + 0x7FFFu + ((v.u >> 16) & 1u)) >> 16);
}
DEV float bf2f(unsigned short s) {
  union { unsigned u; float f; } v; v.u = ((unsigned)s) << 16;
  return v.f;
}

DEV void mfma16(f32x4& d, const s16x8& a, const s16x8& b) {
  d = __builtin_amdgcn_mfma_f32_16x16x32_bf16(
      __builtin_bit_cast(bf16x8, a), __builtin_bit_cast(bf16x8, b), d, 0, 0, 0);
}

typedef const unsigned int gu32 __attribute__((address_space(1)));
typedef unsigned int lu32 __attribute__((address_space(3)));
DEV void gl_lds16(const void* g, void* l) {
  __builtin_amdgcn_global_load_lds((gu32*)g, (lu32*)l, 16, 0, 0);
}

// ---------------------------------------------------------------------------
// Weight transpose fp32 (K x N, submatrix) -> bf16 (N x Kp) at dst rowOff.
// ilv=1: interleave-16 row mapping dstRow = (n/16)*32 + (n%16) + rowOff.
// ---------------------------------------------------------------------------
__global__ void transpose_w(const float* __restrict__ src, int srcLd, int K,
                            int colOff, int nCols,
                            unsigned short* __restrict__ dst, int dstLd, int rowOff,
                            int ilv)
{
  __shared__ float tile[32][33];
  int tx = threadIdx.x & 31, ty = threadIdx.x >> 5;
  int k0 = blockIdx.y * 32, n0 = blockIdx.x * 32;
#pragma unroll
  for (int r = 0; r < 4; ++r) {
    int kk = k0 + ty + r * 8;
    int nn = n0 + tx;
    if (kk < K && nn < nCols) tile[ty + r * 8][tx] = src[(size_t)kk * srcLd + colOff + nn];
  }
  __syncthreads();
#pragma unroll
  for (int r = 0; r < 4; ++r) {
    int nn = n0 + ty + r * 8;
    int kk = k0 + tx;
    if (nn < nCols && kk < K) {
      int row = ilv ? (((nn >> 4) << 5) + (nn & 15) + rowOff) : (rowOff + nn);
      dst[(size_t)row * dstLd + kk] = f2bf(tile[tx][ty + r * 8]);
    }
  }
}

// ---------------------------------------------------------------------------
__global__ void biaspad_kernel(const float* __restrict__ b, float* __restrict__ out)
{
  int n = blockIdx.x * 256 + threadIdx.x;
  if (n >= 5632) return;
  int bb = n >> 4, i = n & 15;
  int src = ((bb >> 1) << 4) + i;
  float v = 0.f;
  if (src < 2730) v = (bb & 1) ? b[2730 + src] : b[src];
  out[n] = v;
}

// ---------------------------------------------------------------------------
__global__ void ada_kernel(const float* __restrict__ c, const float* __restrict__ w,
                           const float* __restrict__ b, float* __restrict__ ada)
{
  __shared__ float cs[1024];
  int bb = blockIdx.y;
  int j = blockIdx.x * 256 + threadIdx.x;
  for (int i = threadIdx.x; i < 1024; i += 256) {
    float v = c[bb * 1024 + i];
    cs[i] = v / (1.f + __expf(-v));
  }
  __syncthreads();
  float acc = b[j];
  for (int k = 0; k < 1024; ++k) acc = fmaf(cs[k], w[(size_t)k * 6144 + j], acc);
  ada[bb * 6144 + j] = acc;
}

// ---------------------------------------------------------------------------
__global__ void rmsmod_kernel(const float* __restrict__ x, const float* __restrict__ nsc,
                              const float* __restrict__ ada, int shOff, int scOff,
                              unsigned short* __restrict__ out)
{
  int row = blockIdx.x;
  int t = threadIdx.x;
  const f32x4* xr = (const f32x4*)(x + (size_t)row * 1024);
  f32x4 v = xr[t];
  float ss = v[0]*v[0] + v[1]*v[1] + v[2]*v[2] + v[3]*v[3];
#pragma unroll
  for (int off = 32; off >= 1; off >>= 1) ss += __shfl_xor(ss, off, 64);
  __shared__ float red[4];
  int lane = t & 63, wv = t >> 6;
  if (lane == 0) red[wv] = ss;
  __syncthreads();
  float tot = red[0] + red[1] + red[2] + red[3];
  float rms = rsqrtf(tot * (1.f / 1024.f) + 1e-6f);
  int bb = row >> 12;
  const float* ab = ada + bb * 6144;
  s16x4 o;
#pragma unroll
  for (int i = 0; i < 4; ++i) {
    int col = t * 4 + i;
    float xn = v[i] * rms * nsc[col];
    float val = xn * (1.f + ab[scOff + col]) + ab[shOff + col];
    o[i] = (short)f2bf(val);
  }
  *(s16x4*)(out + (size_t)row * 1024 + t * 4) = o;
}

// ---------------------------------------------------------------------------
// gemm256: C = A(bf16 MxK, lda) * BT(bf16 NxK, ldb)^T + bias.
// 256x256 tile, BK=64, 8 waves (2Mx4N). Per K-tile: 24 ds_reads up front
// (compiler emits exact counted lgkmcnt before each MFMA cluster), four
// 16-MFMA setprio clusters, 2 barriers, counted vmcnt(4).
//   [reads a0,b0,b1,a1][Q00][Q01] BAR [stageB(kt+2)][Q11][vmcnt(4)] BAR
//   [stageA(kt+2)][Q10]
// Hazard proof: B-region reads drained before Q01 (per-wave) -> all waves at
// BAR-mid -> stage-B safe. A-region reads drained before Q11 -> BAR-late ->
// stage-A safe. vmcnt(4) at BAR-late forces tile kt+1 fully landed (oldest
// outstanding = A(kt+1) [+B(kt+1)]) before any wave reads it.
// EPI 0: bf16 +bias | 1: silu-pair interleave -> Nout=N/2 | 2: f32 res+gate.
// Requires M%256==0, N%256==0, K%64==0, K/64>=2, grid%8==0.
// ---------------------------------------------------------------------------
template<int EPI>
__global__ __launch_bounds__(512, 2) void gemm256(
    const unsigned short* __restrict__ A, int lda,
    const unsigned short* __restrict__ BT, int ldb,
    int N, int K,
    const float* __restrict__ bias,
    void* __restrict__ Cout, int Nout,
    const float* __restrict__ res,
    const float* __restrict__ ada, int gateOff)
{
  __shared__ __align__(16) char lds[131072];

  const int tid = threadIdx.x;
  const int lane = tid & 63;
  const int wv = tid >> 6;
  const int wr = wv >> 2;        // 0..1  (M half)
  const int wn = wv & 3;         // 0..3  (N quarter)
  const int g = lane >> 4, r16 = lane & 15;

  // XCD-aware bijective block swizzle (grid % 8 == 0)
  const int nwg = gridDim.x * gridDim.y;
  const int bid = blockIdx.x + gridDim.x * blockIdx.y;
  const int qq = nwg >> 3;
  const int swz = (bid & 7) * qq + (bid >> 3);
  const int m0 = (swz / gridDim.x) * 256;
  const int n0 = (swz % gridDim.x) * 256;

  const int nkt = K >> 6;

  auto stageB = [&](int t) {
    if (t >= nkt) return;
    const int bs = t & 1;
#pragma unroll
    for (int it = 0; it < 4; ++it) {
      const int cidx = it * 512 + tid;
      const int rl = cidx >> 3, cc = cidx & 7;
      const unsigned short* src =
          BT + (size_t)(n0 + rl) * ldb + t * 64 + ((cc ^ (rl & 7)) << 3);
      gl_lds16(src, lds + 65536 + bs * 32768 + cidx * 16);
    }
  };
  auto stageA = [&](int t) {
    if (t >= nkt) return;
    const int bs = t & 1;
#pragma unroll
    for (int it = 0; it < 4; ++it) {
      const int cidx = it * 512 + tid;
      const int rl = cidx >> 3, cc = cidx & 7;
      const unsigned short* src =
          A + (size_t)(m0 + rl) * lda + t * 64 + ((cc ^ (rl & 7)) << 3);
      gl_lds16(src, lds + bs * 32768 + cidx * 16);
    }
  };

  f32x4 acc[8][4];
#pragma unroll
  for (int m = 0; m < 8; ++m)
#pragma unroll
    for (int n = 0; n < 4; ++n) { acc[m][n][0]=0.f; acc[m][n][1]=0.f; acc[m][n][2]=0.f; acc[m][n][3]=0.f; }

  int swzk[2];
#pragma unroll
  for (int ks = 0; ks < 2; ++ks) swzk[ks] = (((ks << 2) + g) ^ (r16 & 7)) << 4;
  int arow0[4], arow1[4], brow0[2], brow1[2];
#pragma unroll
  for (int m = 0; m < 4; ++m) {
    arow0[m] = (wr * 128 + m * 16 + r16) * 128;
    arow1[m] = (wr * 128 + 64 + m * 16 + r16) * 128;
  }
#pragma unroll
  for (int n = 0; n < 2; ++n) {
    brow0[n] = 65536 + (wn * 64 + n * 16 + r16) * 128;
    brow1[n] = 65536 + (wn * 64 + 32 + n * 16 + r16) * 128;
  }

  // prologue: tiles 0,1 staged; vmcnt(8) -> tile 0 landed
  stageB(0); stageA(0); stageB(1); stageA(1);
  asm volatile("s_waitcnt vmcnt(8)" ::: "memory");
  __builtin_amdgcn_s_barrier();

  for (int kt = 0; kt < nkt; ++kt) {
    const int boff = (kt & 1) * 32768;
    s16x8 a0[4][2], a1[4][2], b0[2][2], b1[2][2];
    // ---- all reads for this K-tile (compiler counts lgkm exactly) ----
#pragma unroll
    for (int m = 0; m < 4; ++m)
#pragma unroll
      for (int ks = 0; ks < 2; ++ks)
        a0[m][ks] = *(const s16x8*)(lds + boff + arow0[m] + swzk[ks]);
#pragma unroll
    for (int n = 0; n < 2; ++n)
#pragma unroll
      for (int ks = 0; ks < 2; ++ks)
        b0[n][ks] = *(const s16x8*)(lds + boff + brow0[n] + swzk[ks]);
#pragma unroll
    for (int n = 0; n < 2; ++n)
#pragma unroll
      for (int ks = 0; ks < 2; ++ks)
        b1[n][ks] = *(const s16x8*)(lds + boff + brow1[n] + swzk[ks]);
#pragma unroll
    for (int m = 0; m < 4; ++m)
#pragma unroll
      for (int ks = 0; ks < 2; ++ks)
        a1[m][ks] = *(const s16x8*)(lds + boff + arow1[m] + swzk[ks]);
    // ---- Q00 ----
    __builtin_amdgcn_s_setprio(1);
#pragma unroll
    for (int m = 0; m < 4; ++m)
#pragma unroll
      for (int n = 0; n < 2; ++n)
#pragma unroll
        for (int ks = 0; ks < 2; ++ks)
          mfma16(acc[m][n], a0[m][ks], b0[n][ks]);
    __builtin_amdgcn_s_setprio(0);
    // ---- Q01 ----
    __builtin_amdgcn_s_setprio(1);
#pragma unroll
    for (int m = 0; m < 4; ++m)
#pragma unroll
      for (int n = 0; n < 2; ++n)
#pragma unroll
        for (int ks = 0; ks < 2; ++ks)
          mfma16(acc[m][2 + n], a0[m][ks], b1[n][ks]);
    __builtin_amdgcn_s_setprio(0);
    __builtin_amdgcn_s_barrier();          // BAR-mid: all B-reads drained
    // ---- stage B(kt+2), Q11 ----
    stageB(kt + 2);
    __builtin_amdgcn_s_setprio(1);
#pragma unroll
    for (int m = 0; m < 4; ++m)
#pragma unroll
      for (int n = 0; n < 2; ++n)
#pragma unroll
        for (int ks = 0; ks < 2; ++ks)
          mfma16(acc[4 + m][2 + n], a1[m][ks], b1[n][ks]);
    __builtin_amdgcn_s_setprio(0);
    if (kt + 2 < nkt) asm volatile("s_waitcnt vmcnt(4)" ::: "memory");
    else              asm volatile("s_waitcnt vmcnt(0)" ::: "memory");
    __builtin_amdgcn_s_barrier();          // BAR-late: A drained + kt+1 landed
    // ---- stage A(kt+2), Q10 ----
    stageA(kt + 2);
    __builtin_amdgcn_s_setprio(1);
#pragma unroll
    for (int m = 0; m < 4; ++m)
#pragma unroll
      for (int n = 0; n < 2; ++n)
#pragma unroll
        for (int ks = 0; ks < 2; ++ks)
          mfma16(acc[4 + m][n], a1[m][ks], b0[n][ks]);
    __builtin_amdgcn_s_setprio(0);
  }

  if (EPI == 0) {
    unsigned short* Co = (unsigned short*)Cout;
#pragma unroll
    for (int fm = 0; fm < 8; ++fm)
#pragma unroll
      for (int fn = 0; fn < 4; ++fn)
#pragma unroll
        for (int r = 0; r < 4; ++r) {
          int rg = m0 + wr * 128 + fm * 16 + g * 4 + r;
          int cg = n0 + wn * 64 + fn * 16 + r16;
          Co[(size_t)rg * Nout + cg] = f2bf(acc[fm][fn][r] + bias[cg]);
        }
  } else if (EPI == 1) {
    unsigned short* Co = (unsigned short*)Cout;
#pragma unroll
    for (int fm = 0; fm < 8; ++fm)
#pragma unroll
      for (int p = 0; p < 2; ++p)
#pragma unroll
        for (int r = 0; r < 4; ++r) {
          int rg = m0 + wr * 128 + fm * 16 + g * 4 + r;
          int cg = n0 + wn * 64 + (2 * p) * 16 + r16;
          float v1 = acc[fm][2 * p][r] + bias[cg];
          float v2 = acc[fm][2 * p + 1][r] + bias[cg + 16];
          float h = v1 / (1.f + __expf(-v1)) * v2;
          int hcol = (n0 >> 1) + wn * 32 + p * 16 + r16;
          Co[(size_t)rg * Nout + hcol] = f2bf(h);
        }
  } else {
    float* Co = (float*)Cout;
#pragma unroll
    for (int fm = 0; fm < 8; ++fm)
#pragma unroll
      for (int fn = 0; fn < 4; ++fn)
#pragma unroll
        for (int r = 0; r < 4; ++r) {
          int rg = m0 + wr * 128 + fm * 16 + g * 4 + r;
          int cg = n0 + wn * 64 + fn * 16 + r16;
          float v = acc[fm][fn][r] + bias[cg];
          int bb = rg >> 12;
          float gate = ada[bb * 6144 + gateOff + cg];
          size_t idx = (size_t)rg * Nout + cg;
          Co[idx] = res[idx] + gate * v;
        }
  }
}

// ---------------------------------------------------------------------------
// GEMM 128x128 (2-barrier structure) for the out-proj GEMM.
// MODE 1: f32 store res + gate*(v+b)
// ---------------------------------------------------------------------------
template<int MODE>
__global__ void gemm128(const unsigned short* __restrict__ A, int lda,
                        const unsigned short* __restrict__ BT,
                        int N, int K,
                        const float* __restrict__ bias,
                        void* __restrict__ Cout,
                        const float* __restrict__ res,
                        const float* __restrict__ ada, int gateOff, int mOff)
{
  __shared__ __align__(16) unsigned short As[128 * 32];
  __shared__ __align__(16) unsigned short Bs[128 * 32];

  const int tid = threadIdx.x;
  const int lane = tid & 63;
  const int wv = tid >> 6;
  const int wr = wv >> 1, wc = wv & 1;
  const int g = lane >> 4, r16 = lane & 15;
  const int m0 = blockIdx.y * 128, n0 = blockIdx.x * 128;

  const int c0 = tid, c1 = 256 + tid;
  const int ra0 = c0 >> 2, ra1 = c1 >> 2;
  const int k0 = ((c0 & 3) ^ ((ra0 >> 1) & 3)) * 8;
  const int k1 = ((c1 & 3) ^ ((ra1 >> 1) & 3)) * 8;
  const unsigned short* ga0 = A + (size_t)(m0 + ra0) * lda + k0;
  const unsigned short* ga1 = A + (size_t)(m0 + ra1) * lda + k1;
  const unsigned short* gb0 = BT + (size_t)(n0 + ra0) * K + k0;
  const unsigned short* gb1 = BT + (size_t)(n0 + ra1) * K + k1;
  unsigned short* la0 = As + c0 * 8;
  unsigned short* la1 = As + c1 * 8;
  unsigned short* lb0 = Bs + c0 * 8;
  unsigned short* lb1 = Bs + c1 * 8;

  f32x4 acc[4][4];
#pragma unroll
  for (int m = 0; m < 4; ++m)
#pragma unroll
    for (int n = 0; n < 4; ++n) { acc[m][n][0]=0.f; acc[m][n][1]=0.f; acc[m][n][2]=0.f; acc[m][n][3]=0.f; }

  int aoff[4], boff[4];
#pragma unroll
  for (int m = 0; m < 4; ++m) {
    int rl = wr * 64 + m * 16 + r16;
    aoff[m] = rl * 32 + (g ^ ((rl >> 1) & 3)) * 8;
    int rb = wc * 64 + m * 16 + r16;
    boff[m] = rb * 32 + (g ^ ((rb >> 1) & 3)) * 8;
  }

  const int nk = K >> 5;
  for (int kt = 0; kt < nk; ++kt) {
    __syncthreads();
    const int ko = kt * 32;
    gl_lds16(ga0 + ko, la0);
    gl_lds16(ga1 + ko, la1);
    gl_lds16(gb0 + ko, lb0);
    gl_lds16(gb1 + ko, lb1);
    __syncthreads();
    s16x8 af[4], bf[4];
#pragma unroll
    for (int m = 0; m < 4; ++m) af[m] = *(const s16x8*)(As + aoff[m]);
#pragma unroll
    for (int n = 0; n < 4; ++n) bf[n] = *(const s16x8*)(Bs + boff[n]);
#pragma unroll
    for (int m = 0; m < 4; ++m)
#pragma unroll
      for (int n = 0; n < 4; ++n) mfma16(acc[m][n], af[m], bf[n]);
  }

#pragma unroll
  for (int m = 0; m < 4; ++m) {
#pragma unroll
    for (int n = 0; n < 4; ++n) {
#pragma unroll
      for (int r = 0; r < 4; ++r) {
        int rg = m0 + wr * 64 + m * 16 + g * 4 + r;
        int cg = n0 + wc * 64 + n * 16 + r16;
        float v = acc[m][n][r] + bias[cg];
        size_t idx = (size_t)rg * N + cg;
        if (MODE == 0 || MODE == 2) {
          ((unsigned short*)Cout)[idx] = f2bf(v);
        } else {
          int bb = (mOff + rg) >> 12;
          float gate = ada[bb * 6144 + gateOff + cg];
          ((float*)Cout)[idx] = res[idx] + gate * v;
        }
      }
    }
  }
}

// ---------------------------------------------------------------------------
__global__ void vtrans_kernel(const unsigned short* __restrict__ qkv,
                              unsigned short* __restrict__ vT)
{
  __shared__ unsigned short tl[64][72];
  int pidx = blockIdx.x;
  int w = pidx >> 4, h = pidx & 15;
  int t = threadIdx.x;
  for (int jb = 0; jb < 4; ++jb) {
    int jl = t >> 2, dc = t & 3;
    const unsigned short* srcp =
        qkv + (size_t)(w * 256 + jb * 64 + jl) * 3072 + 2048 + h * 64 + dc * 16;
    s16x8 v0 = *(const s16x8*)(srcp);
    s16x8 v1 = *(const s16x8*)(srcp + 8);
    if (jb) __syncthreads();
    *(s16x8*)(&tl[jl][dc * 16]) = v0;
    *(s16x8*)(&tl[jl][dc * 16 + 8]) = v1;
    __syncthreads();
    int dl = t >> 2, jc = t & 3;
    s16x8 o0, o1;
#pragma unroll
    for (int i = 0; i < 8; ++i) {
      o0[i] = (short)tl[jc * 16 + i][dl];
      o1[i] = (short)tl[jc * 16 + 8 + i][dl];
    }
    unsigned short* dstp = vT + (size_t)pidx * (64 * 256) + (size_t)dl * 256 + jb * 64 + jc * 16;
    *(s16x8*)(dstp) = o0;
    *(s16x8*)(dstp + 8) = o1;
  }
}

// ---------------------------------------------------------------------------
__global__ __launch_bounds__(256, 1) void attn_kernel(
    const unsigned short* __restrict__ qkv,
    const unsigned short* __restrict__ vT,
    unsigned short* __restrict__ attnout)
{
  __shared__ __align__(16) unsigned short Kl[256 * 64];
  __shared__ __align__(16) unsigned short Vl[64 * 256];
  __shared__ __align__(16) unsigned short Pl[4][64 * 88];

  const int tid = threadIdx.x;
  const int lane = tid & 63;
  const int wv = tid >> 6;
  const int g = lane >> 4, r16 = lane & 15;
  const int p = blockIdx.x;
  const int w = p >> 4, h = p & 15;
  const float hh = (float)h;
  const float F = 0.4152410118609203f; // log2(10000)/32

#pragma unroll
  for (int it = 0; it < 4; ++it) {
    int idx = it * 256 + tid;
    int j = idx >> 2;
    int c = idx & 3;
    const unsigned short* kg = qkv + (size_t)(w * 256 + j) * 3072 + 1024 + h * 64;
    s16x8 lo = *(const s16x8*)(kg + c * 8);
    s16x8 hi = *(const s16x8*)(kg + 32 + c * 8);
    s16x8 plo, phi;
#pragma unroll
    for (int i2 = 0; i2 < 4; ++i2) {
      float f1 = exp2f(-(float)(c * 4 + i2) * F);
      float f2 = exp2f(-(float)(16 + c * 4 + i2) * F);
      float s1, c1s, s2, c2s;
      sincosf(hh * f1, &s1, &c1s);
      sincosf(hh * f2, &s2, &c2s);
#pragma unroll
      for (int u = 0; u < 2; ++u) {
        int i = i2 * 2 + u;
        float a = bf2f((unsigned short)lo[i]);
        float b = bf2f((unsigned short)hi[i]);
        plo[i] = (short)f2bf(a * c1s - b * s1);
        phi[i] = (short)f2bf(b * c2s + a * s2);
      }
    }
    int swzL = c ^ (j & 7);
    int swzH = (c + 4) ^ (j & 7);
    *(s16x8*)(Kl + j * 64 + swzL * 8) = plo;
    *(s16x8*)(Kl + j * 64 + swzH * 8) = phi;
  }
  {
    const unsigned short* vg = vT + (size_t)p * (64 * 256);
#pragma unroll
    for (int it = 0; it < 8; ++it) {
      int idx = it * 256 + tid;
      int d = idx >> 5;
      int c = idx & 31;
      s16x8 val = *(const s16x8*)(vg + d * 256 + c * 8);
      int cs = (c & ~7) | ((c ^ d) & 7);
      *(s16x8*)(Vl + d * 256 + cs * 8) = val;
    }
  }

  s16x8 qa[4][2];
  {
    float cs0[4], sn0[4], cs1[4], sn1[4];
#pragma unroll
    for (int i2 = 0; i2 < 4; ++i2) {
      float f1 = exp2f(-(float)(g * 4 + i2) * F);
      float f2 = exp2f(-(float)(16 + g * 4 + i2) * F);
      sincosf(hh * f1, &sn0[i2], &cs0[i2]);
      sincosf(hh * f2, &sn1[i2], &cs1[i2]);
    }
#pragma unroll
    for (int m = 0; m < 4; ++m) {
      const unsigned short* qg =
          qkv + (size_t)(w * 256 + wv * 64 + m * 16 + r16) * 3072 + h * 64;
      s16x8 lo = *(const s16x8*)(qg + g * 8);
      s16x8 hi = *(const s16x8*)(qg + 32 + g * 8);
      s16x8 plo, phi;
#pragma unroll
      for (int i = 0; i < 8; ++i) {
        int i2 = i >> 1;
        float a = bf2f((unsigned short)lo[i]);
        float b = bf2f((unsigned short)hi[i]);
        plo[i] = (short)f2bf(a * cs0[i2] - b * sn0[i2]);
        phi[i] = (short)f2bf(b * cs1[i2] + a * sn1[i2]);
      }
      qa[m][0] = plo;
      qa[m][1] = phi;
    }
  }

  __syncthreads();

  f32x4 accO[4][4];
  float Mx[4][4], Ls[4][4];
#pragma unroll
  for (int m = 0; m < 4; ++m)
#pragma unroll
    for (int r = 0; r < 4; ++r) {
      Mx[m][r] = -3.0e38f;
      Ls[m][r] = 0.f;
      accO[m][r][0]=0.f; accO[m][r][1]=0.f; accO[m][r][2]=0.f; accO[m][r][3]=0.f;
    }
  unsigned short* Pw = &Pl[wv][0];
  const float zs = 0.125f * 1.44269504f;

  for (int kb = 0; kb < 4; ++kb) {
    f32x4 s[4][4];
#pragma unroll
    for (int m = 0; m < 4; ++m)
#pragma unroll
      for (int jt = 0; jt < 4; ++jt) { s[m][jt][0]=0.f; s[m][jt][1]=0.f; s[m][jt][2]=0.f; s[m][jt][3]=0.f; }

#pragma unroll
    for (int jt = 0; jt < 4; ++jt) {
      int j = kb * 64 + jt * 16 + r16;
      s16x8 bk0 = *(const s16x8*)(Kl + j * 64 + ((g ^ (j & 7)) * 8));
      s16x8 bk1 = *(const s16x8*)(Kl + j * 64 + (((4 + g) ^ (j & 7)) * 8));
#pragma unroll
      for (int m = 0; m < 4; ++m) {
        mfma16(s[m][jt], qa[m][0], bk0);
        mfma16(s[m][jt], qa[m][1], bk1);
      }
    }

#pragma unroll
    for (int m = 0; m < 4; ++m) {
#pragma unroll
      for (int r = 0; r < 4; ++r) {
        float mx = fmaxf(fmaxf(s[m][0][r], s[m][1][r]), fmaxf(s[m][2][r], s[m][3][r]));
        mx = fmaxf(mx, __shfl_xor(mx, 1, 16));
        mx = fmaxf(mx, __shfl_xor(mx, 2, 16));
        mx = fmaxf(mx, __shfl_xor(mx, 4, 16));
        mx = fmaxf(mx, __shfl_xor(mx, 8, 16));
        float Mn = fmaxf(Mx[m][r], mx * zs);
        float fsc = exp2f(Mx[m][r] - Mn);
        Mx[m][r] = Mn;
        float ps = 0.f;
#pragma unroll
        for (int jt = 0; jt < 4; ++jt) {
          float pv = exp2f(s[m][jt][r] * zs - Mn);
          s[m][jt][r] = pv;
          ps += pv;
        }
        ps += __shfl_xor(ps, 1, 16);
        ps += __shfl_xor(ps, 2, 16);
        ps += __shfl_xor(ps, 4, 16);
        ps += __shfl_xor(ps, 8, 16);
        Ls[m][r] = Ls[m][r] * fsc + ps;
#pragma unroll
        for (int dt = 0; dt < 4; ++dt) accO[m][dt][r] *= fsc;
      }
    }

#pragma unroll
    for (int m = 0; m < 4; ++m)
#pragma unroll
      for (int jt = 0; jt < 4; ++jt)
#pragma unroll
        for (int r = 0; r < 4; ++r) {
          int q = m * 16 + g * 4 + r;
          int jj = jt * 16 + r16;
          Pw[q * 88 + jj] = f2bf(s[m][jt][r]);
        }
    asm volatile("s_waitcnt lgkmcnt(0)" ::: "memory");
    __builtin_amdgcn_sched_barrier(0);

#pragma unroll
    for (int c = 0; c < 2; ++c) {
      s16x8 pa[4];
#pragma unroll
      for (int m = 0; m < 4; ++m)
        pa[m] = *(const s16x8*)(Pw + (m * 16 + r16) * 88 + c * 32 + g * 8);
#pragma unroll
      for (int dt = 0; dt < 4; ++dt) {
        int d = dt * 16 + r16;
        int cch = kb * 8 + c * 4 + g;
        int csz = (cch & ~7) | ((cch ^ d) & 7);
        s16x8 vb = *(const s16x8*)(Vl + d * 256 + csz * 8);
#pragma unroll
        for (int m = 0; m < 4; ++m) mfma16(accO[m][dt], pa[m], vb);
      }
    }
    asm volatile("s_waitcnt lgkmcnt(0)" ::: "memory");
    __builtin_amdgcn_sched_barrier(0);
  }

#pragma unroll
  for (int m = 0; m < 4; ++m)
#pragma unroll
    for (int dt = 0; dt < 4; ++dt)
#pragma unroll
      for (int r = 0; r < 4; ++r) {
        int rg = w * 256 + wv * 64 + m * 16 + g * 4 + r;
        int cg = h * 64 + dt * 16 + r16;
        float val = accO[m][dt][r] / Ls[m][r];
        attnout[(size_t)rg * 1024 + cg] = f2bf(val);
      }
}

// ---------------------------------------------------------------------------
extern "C" void kernel_launch(void* const* d_in, const int* in_sizes, int n_in,
                              void* d_out, int out_size, void* d_ws, size_t ws_size,
                              hipStream_t stream)
{
  const float* x    = (const float*)d_in[0];
  const float* c    = (const float*)d_in[1];
  const float* n1s  = (const float*)d_in[2];
  const float* n2s  = (const float*)d_in[3];
  const float* adaW = (const float*)d_in[4];
  const float* adaB = (const float*)d_in[5];
  const float* qkvW = (const float*)d_in[6];
  const float* qkvB = (const float*)d_in[7];
  const float* outW = (const float*)d_in[8];
  const float* outB = (const float*)d_in[9];
  const float* w12W = (const float*)d_in[10];
  const float* w12B = (const float*)d_in[11];
  const float* w3W  = (const float*)d_in[12];
  const float* w3B  = (const float*)d_in[13];

  char* ws = (char*)d_ws;
  constexpr size_t OFF_ADA  = 0;
  constexpr size_t OFF_QKVT = 98304;
  constexpr size_t OFF_OUTT = OFF_QKVT + 6291456;
  constexpr size_t OFF_W12T = OFF_OUTT + 2097152;
  constexpr size_t OFF_W3T  = OFF_W12T + 11534336;
  constexpr size_t OFF_BPAD = OFF_W3T + 5767168;
  constexpr size_t OFF_XM   = OFF_BPAD + 22528;
  constexpr size_t OFF_BIG  = OFF_XM + 33554432;
  constexpr size_t OFF_QKVC = OFF_BIG;               // 50.3 MB (chunked qkv)
  constexpr size_t OFF_VTC  = OFF_BIG + 50331648;    // 16.8 MB
  constexpr size_t OFF_ATTC = OFF_BIG + 67108864;    // 16.8 MB
  constexpr size_t OFF_HBUF = OFF_BIG;               // 92.3 MB (full-M h)

  float* ada            = (float*)(ws + OFF_ADA);
  unsigned short* qkvT  = (unsigned short*)(ws + OFF_QKVT);
  unsigned short* outT  = (unsigned short*)(ws + OFF_OUTT);
  unsigned short* w12T  = (unsigned short*)(ws + OFF_W12T);
  unsigned short* w3T   = (unsigned short*)(ws + OFF_W3T);
  float* biasPad        = (float*)(ws + OFF_BPAD);
  unsigned short* xm    = (unsigned short*)(ws + OFF_XM);
  unsigned short* qkvbC = (unsigned short*)(ws + OFF_QKVC);
  unsigned short* vTbC  = (unsigned short*)(ws + OFF_VTC);
  unsigned short* attnC = (unsigned short*)(ws + OFF_ATTC);
  unsigned short* hbuf  = (unsigned short*)(ws + OFF_HBUF);
  float* x2             = (float*)d_out;

  hipMemsetAsync(w12T, 0, 11534336, stream);
  hipMemsetAsync(w3T, 0, 5767168, stream);
  transpose_w<<<dim3(96, 32), 256, 0, stream>>>(qkvW, 3072, 1024, 0, 3072, qkvT, 1024, 0, 0);
  transpose_w<<<dim3(32, 32), 256, 0, stream>>>(outW, 1024, 1024, 0, 1024, outT, 1024, 0, 0);
  transpose_w<<<dim3(86, 32), 256, 0, stream>>>(w12W, 5460, 1024, 0, 2730, w12T, 1024, 0, 1);
  transpose_w<<<dim3(86, 32), 256, 0, stream>>>(w12W, 5460, 1024, 2730, 2730, w12T, 1024, 16, 1);
  transpose_w<<<dim3(32, 86), 256, 0, stream>>>(w3W, 1024, 2730, 0, 1024, w3T, 2816, 0, 0);
  biaspad_kernel<<<22, 256, 0, stream>>>(w12B, biasPad);
  ada_kernel<<<dim3(24, 4), 256, 0, stream>>>(c, adaW, adaB, ada);

  // --- attention branch (2 chunks of 8192 rows = 32 windows) ---
  rmsmod_kernel<<<16384, 256, 0, stream>>>(x, n1s, ada, 0, 1024, xm);
  for (int ch = 0; ch < 2; ++ch) {
    const size_t ro = (size_t)ch * 8192;
    gemm256<0><<<dim3(12, 32), 512, 0, stream>>>(
        xm + ro * 1024, 1024, qkvT, 1024, 3072, 1024, qkvB, qkvbC, 3072,
        nullptr, nullptr, 0);
    vtrans_kernel<<<512, 256, 0, stream>>>(qkvbC, vTbC);
    attn_kernel<<<512, 256, 0, stream>>>(qkvbC, vTbC, attnC);
    gemm128<1><<<dim3(8, 64), 256, 0, stream>>>(
        attnC, 1024, outT, 1024, 1024, outB, x2 + ro * 1024, x + ro * 1024,
        ada, 2048, (int)ro);
  }

  // --- MLP branch (full M = 16384) ---
  rmsmod_kernel<<<16384, 256, 0, stream>>>(x2, n2s, ada, 3072, 4096, xm);
  gemm256<1><<<dim3(22, 64), 512, 0, stream>>>(
      xm, 1024, w12T, 1024, 5632, 1024, biasPad, hbuf, 2816,
      nullptr, nullptr, 0);
  gemm256<2><<<dim3(4, 64), 512, 0, stream>>>(
      hbuf, 2816, w3T, 2816, 1024, 2816, w3B, x2, 1024,
      x2, ada, 5120);
}